// Round 8
// baseline (315.808 us; speedup 1.0000x reference)
//
#include <hip/hip_runtime.h>
#include <hip/hip_bf16.h>

#define TT 2048

typedef __attribute__((ext_vector_type(8))) short bf16x8;
typedef __attribute__((ext_vector_type(4))) float f32x4;
typedef __attribute__((ext_vector_type(16))) float f32x16;
typedef __attribute__((ext_vector_type(2))) int i32x2;

__device__ __forceinline__ short f2b(float f) {
  union { float f; unsigned u; } a; a.f = f;
  unsigned r = a.u + 0x7fffu + ((a.u >> 16) & 1u);
  return (short)(r >> 16);
}
__device__ __forceinline__ float b2f(short s) {
  union { unsigned u; float f; } a; a.u = ((unsigned)(unsigned short)s) << 16;
  return a.f;
}
__device__ __forceinline__ unsigned cvtpk(float lo, float hi) {
  unsigned r;
  asm("v_cvt_pk_bf16_f32 %0, %1, %2" : "=v"(r) : "v"(lo), "v"(hi));
  return r;
}
__device__ __forceinline__ float max3f(float a, float b, float c) {
  float d;
  asm("v_max3_f32 %0, %1, %2, %3" : "=v"(d) : "v"(a), "v"(b), "v"(c));
  return d;
}
__device__ __forceinline__ float ex2(float x) {
#if __has_builtin(__builtin_amdgcn_exp2f)
  return __builtin_amdgcn_exp2f(x);
#else
  return exp2f(x);
#endif
}
// async global->LDS, 16B per lane; lds dest = wave-uniform base + lane*16
__device__ __forceinline__ void gll16(const void* g, void* l) {
  __builtin_amdgcn_global_load_lds(
      (const __attribute__((address_space(1))) unsigned int*)g,
      (__attribute__((address_space(3))) unsigned int*)l, 16, 0, 0);
}
// exchange high-32 lanes of a with low-32 lanes of b
__device__ __forceinline__ void swap_halves(unsigned &a, unsigned &b, bool hi) {
#if __has_builtin(__builtin_amdgcn_permlane32_swap)
  i32x2 r = __builtin_amdgcn_permlane32_swap((int)a, (int)b, false, false);
  a = (unsigned)r[0]; b = (unsigned)r[1];
#else
  unsigned as = (unsigned)__shfl_xor((int)a, 32);
  unsigned bs = (unsigned)__shfl_xor((int)b, 32);
  unsigned na = hi ? bs : a;
  unsigned nb = hi ? b : as;
  a = na; b = nb;
#endif
}

// 16 f32 P-values (one 32-row S^T fragment) -> two PV A-frags
__device__ __forceinline__ void p_to_frags(const f32x16 p, bool hi, bf16x8* f0, bf16x8* f1) {
  unsigned A[4][2];
#pragma unroll
  for (int u = 0; u < 4; ++u)
#pragma unroll
    for (int c = 0; c < 2; ++c)
      A[u][c] = cvtpk(p[4 * u + 2 * c], p[4 * u + 2 * c + 1]);
  swap_halves(A[0][0], A[1][0], hi);
  swap_halves(A[0][1], A[1][1], hi);
  swap_halves(A[2][0], A[3][0], hi);
  swap_halves(A[2][1], A[3][1], hi);
  union { unsigned u[4]; bf16x8 v; } r0, r1;
  r0.u[0] = A[0][0]; r0.u[1] = A[0][1]; r0.u[2] = A[1][0]; r0.u[3] = A[1][1];
  r1.u[0] = A[2][0]; r1.u[1] = A[2][1]; r1.u[2] = A[3][0]; r1.u[3] = A[3][1];
  *f0 = r0.v; *f1 = r1.v;
}

// swizzled LDS access, 128B rows: byte col ^ ((row&7)<<4)
__device__ __forceinline__ bf16x8 lds16(const short* base, int row, int cb) {
  return *reinterpret_cast<const bf16x8*>(
      reinterpret_cast<const char*>(base) + row * 128 + (cb ^ ((row & 7) << 4)));
}

// fused prep: transpose-cast w_qkv (192 blocks) + w_o (64 blocks) + RoPE table (256)
__global__ __launch_bounds__(256) void prep_kernel(const float* __restrict__ w_qkv,
                                                   short* __restrict__ wqkvT,
                                                   const float* __restrict__ w_o,
                                                   short* __restrict__ woT,
                                                   float2* __restrict__ tab) {
  __shared__ float t[64][65];
  const int id = blockIdx.x;
  if (id < 256) {
    const float* src; short* dst; int N, n0, k0;
    if (id < 192) { src = w_qkv; dst = wqkvT; N = 1536; n0 = (id % 24) * 64; k0 = (id / 24) * 64; }
    else { const int i2 = id - 192; src = w_o; dst = woT; N = 512; n0 = (i2 & 7) * 64; k0 = (i2 >> 3) * 64; }
    const int c = threadIdx.x & 63, r4 = threadIdx.x >> 6;
#pragma unroll
    for (int i = 0; i < 16; ++i) {
      const int r = i * 4 + r4;
      t[r][c] = src[(size_t)(k0 + r) * N + n0 + c];
    }
    __syncthreads();
#pragma unroll
    for (int i = 0; i < 16; ++i) {
      const int r = i * 4 + r4;
      dst[(size_t)(n0 + r) * 512 + k0 + c] = f2b(t[c][r]);
    }
  } else {
    const int idx = (id - 256) * 256 + threadIdx.x;  // 65536
    const int i = idx & 31, tt = idx >> 5;
    const float inv_freq = __expf(-(float)i * (9.210340371976184f / 32.0f));
    float sv, cv;
    sincosf((float)tt * inv_freq, &sv, &cv);
    tab[idx] = make_float2(cv, sv);
  }
}

// LayerNorm rows of 512, fp32 in, bf16 out
__global__ __launch_bounds__(256) void ln_kernel(const float* __restrict__ x,
                                                 const float* __restrict__ w,
                                                 const float* __restrict__ b,
                                                 short* __restrict__ h) {
  const int row = blockIdx.x;
  const int tid = threadIdx.x;
  const float2 v = *reinterpret_cast<const float2*>(x + (size_t)row * 512 + tid * 2);
  float s = v.x + v.y;
  float sq = v.x * v.x + v.y * v.y;
  for (int off = 1; off < 64; off <<= 1) { s += __shfl_xor(s, off); sq += __shfl_xor(sq, off); }
  __shared__ float red[8];
  const int wv = tid >> 6;
  if ((tid & 63) == 0) { red[wv] = s; red[wv + 4] = sq; }
  __syncthreads();
  s = red[0] + red[1] + red[2] + red[3];
  sq = red[4] + red[5] + red[6] + red[7];
  const float mu = s * (1.0f / 512.0f);
  const float var = sq * (1.0f / 512.0f) - mu * mu;
  const float inv = rsqrtf(var + 1e-5f);
  const float2 wv2 = *reinterpret_cast<const float2*>(w + tid * 2);
  const float2 bv2 = *reinterpret_cast<const float2*>(b + tid * 2);
  const float h0 = (v.x - mu) * inv * wv2.x + bv2.x;
  const float h1 = (v.y - mu) * inv * wv2.y + bv2.y;
  unsigned u = (unsigned)(unsigned short)f2b(h0) | ((unsigned)(unsigned short)f2b(h1) << 16);
  *reinterpret_cast<unsigned*>(h + (size_t)row * 512 + tid * 2) = u;
}

// 128x128 tile GEMM via global_load_lds, both-sides-swizzled LDS [128][64].
// A[M][512] bf16 row-major, Bt[N][512] bf16 (B transposed).
// EPI=0: bias + fused RoPE, scatter q/k [bh][t][64], v^T [bh][d][t]
// EPI=1: out[row][col] = acc + bias (f32)
template <int EPI>
__global__ __launch_bounds__(256) void gemm128_kernel(const short* __restrict__ A,
                                                      const short* __restrict__ Bt,
                                                      const float* __restrict__ bias,
                                                      const float2* __restrict__ tab,
                                                      void* __restrict__ o0,
                                                      void* __restrict__ o1,
                                                      void* __restrict__ o2) {
  __shared__ short As[128 * 64];
  __shared__ short Bs[128 * 64];
  const int tid = threadIdx.x;
  const int lane = tid & 63, wave = tid >> 6;
  const int lr = lane & 15, lg = lane >> 4;
  const int wm = wave >> 1, wn = wave & 1;
  const int m0 = blockIdx.x * 128, n0 = blockIdx.y * 128;

  const int swz_col = ((lane & 7) ^ ((lane >> 3) & 7)) * 8;
  const short* Ag = A + (size_t)(m0 + wave * 32 + (lane >> 3)) * 512 + swz_col;
  const short* Bg = Bt + (size_t)(n0 + wave * 32 + (lane >> 3)) * 512 + swz_col;
  short* AsW = &As[(wave * 32) * 64];
  short* BsW = &Bs[(wave * 32) * 64];

  f32x4 acc[4][4] = {};

  for (int k0 = 0; k0 < 512; k0 += 64) {
#pragma unroll
    for (int i = 0; i < 4; ++i) {
      gll16(Ag + (size_t)i * 8 * 512 + k0, AsW + i * 8 * 64);
      gll16(Bg + (size_t)i * 8 * 512 + k0, BsW + i * 8 * 64);
    }
    __syncthreads();
#pragma unroll
    for (int ks = 0; ks < 2; ++ks) {
      bf16x8 af[4], bfr[4];
#pragma unroll
      for (int m = 0; m < 4; ++m)
        af[m] = lds16(As, wm * 64 + m * 16 + lr, ks * 64 + lg * 16);
#pragma unroll
      for (int n = 0; n < 4; ++n)
        bfr[n] = lds16(Bs, wn * 64 + n * 16 + lr, ks * 64 + lg * 16);
#pragma unroll
      for (int m = 0; m < 4; ++m)
#pragma unroll
        for (int n = 0; n < 4; ++n)
          acc[m][n] = __builtin_amdgcn_mfma_f32_16x16x32_bf16(af[m], bfr[n], acc[m][n], 0, 0, 0);
    }
    __syncthreads();
  }

  if (EPI == 0) {
    const int base = n0 + wn * 64;             // wave-uniform head window
    const int which = base >> 9;               // 0=q 1=k 2=v
    const int hh = (base & 511) >> 6;
    short* qp = (short*)o0; short* kp = (short*)o1; short* vtp = (short*)o2;
    const float b0 = bias[base + lr], b1 = bias[base + 16 + lr];
    const float b2 = bias[base + 32 + lr], b3 = bias[base + 48 + lr];
    const float QS = 0.125f * 1.4426950408889634f;  // 1/sqrt(dk) * log2(e), q only
#pragma unroll
    for (int m = 0; m < 4; ++m) {
      const int rowb = m0 + wm * 64 + m * 16 + lg * 4;
#pragma unroll
      for (int j = 0; j < 4; ++j) {
        const int t = (rowb + j) & 2047;
        const int bh = ((rowb + j) >> 11) * 8 + hh;
        float v0 = acc[m][0][j] + b0;
        float v1 = acc[m][1][j] + b1;
        float v2 = acc[m][2][j] + b2;
        float v3 = acc[m][3][j] + b3;
        if (which < 2) {
          const float2 cs0 = tab[t * 32 + lr];
          const float2 cs1 = tab[t * 32 + 16 + lr];
          float r0 = v0 * cs0.x - v2 * cs0.y;
          float r2 = v2 * cs0.x + v0 * cs0.y;
          float r1 = v1 * cs1.x - v3 * cs1.y;
          float r3 = v3 * cs1.x + v1 * cs1.y;
          if (which == 0) { r0 *= QS; r1 *= QS; r2 *= QS; r3 *= QS; }
          short* dst = (which == 0 ? qp : kp) + ((size_t)bh * TT + t) * 64;
          dst[lr] = f2b(r0); dst[16 + lr] = f2b(r1);
          dst[32 + lr] = f2b(r2); dst[48 + lr] = f2b(r3);
        } else {
          short* vb = vtp + (size_t)bh * 64 * TT + t;
          vb[(size_t)lr * TT] = f2b(v0);
          vb[(size_t)(16 + lr) * TT] = f2b(v1);
          vb[(size_t)(32 + lr) * TT] = f2b(v2);
          vb[(size_t)(48 + lr) * TT] = f2b(v3);
        }
      }
    }
  } else {
#pragma unroll
    for (int m = 0; m < 4; ++m)
#pragma unroll
      for (int n = 0; n < 4; ++n)
#pragma unroll
        for (int j = 0; j < 4; ++j) {
          const int row = m0 + wm * 64 + m * 16 + lg * 4 + j;
          const int col = n0 + wn * 64 + n * 16 + lr;
          ((float*)o0)[(size_t)row * 512 + col] = acc[m][n][j] + bias[col];
        }
  }
}

// Flash attention, swapped-QK^T 32x32x16, exp2 softmax, T15 2-deep pipeline:
// QK^T(kt) overlaps softmax+PV(kt-1); triple-buffered K/V LDS via gll.
// grid: 1024 linear blocks (XCD-swizzled); 4 waves x 32 q-rows.
__global__ __launch_bounds__(256) void attn_kernel(const short* __restrict__ q,
                                                   const short* __restrict__ k,
                                                   const short* __restrict__ vt,
                                                   const unsigned char* __restrict__ mask,
                                                   short* __restrict__ o) {
  __shared__ short Ks[3][64 * 64];
  __shared__ short Vs[3][64 * 64];
  __shared__ float psc[4][32];
  const int tid = threadIdx.x;
  const int lane = tid & 63, wave = tid >> 6;
  const int l31 = lane & 31, g = lane >> 5;
  const bool hi = (g != 0);
  // bijective XCD swizzle: 1024 blocks, 8 XCDs -> 16 q-tiles of one bh per XCD
  const int nb = (blockIdx.x & 7) * 128 + (blockIdx.x >> 3);
  const int bh = nb >> 4, qt = nb & 15;
  const int bb = bh >> 3, hh = bh & 7;
  const int q0 = qt * 128 + wave * 32;
  const size_t bhT = (size_t)bh * TT;
  const unsigned char* maskb = mask + (size_t)bb * TT;

  // whole-row mask flag (hoisted): 2048 bytes = 512 dwords per batch row
  unsigned mor = 0;
  const unsigned* mw = (const unsigned*)maskb;
#pragma unroll
  for (int i = 0; i < 8; ++i) mor |= mw[lane + 64 * i];
  const bool masked = __any((int)(mor != 0));

  // Q as B-operand frags
  bf16x8 qf[4];
#pragma unroll
  for (int ds = 0; ds < 4; ++ds)
    qf[ds] = *reinterpret_cast<const bf16x8*>(q + (bhT + q0 + l31) * 64 + ds * 16 + g * 8);

  f32x16 oa0 = {}, oa1 = {};
  float m_run = 0.0f, l_run = 0.0f;

  // gll staging: wave w stages K rows [w*16,+16) and V d-rows [w*16,+16), 2 glls each
  const int swz_col = ((lane & 7) ^ ((lane >> 3) & 7)) * 8;
  const int r0 = wave * 16;
  const short* kg0 = k + (bhT + r0 + (lane >> 3)) * 64 + swz_col;
  const short* vg0 = vt + ((size_t)bh * 64 + r0 + (lane >> 3)) * TT + swz_col;

  auto stage = [&](int kt, int buf) {
    gll16(kg0 + (size_t)kt * 4096,          &Ks[buf][r0 * 64]);
    gll16(kg0 + (size_t)kt * 4096 + 8 * 64, &Ks[buf][(r0 + 8) * 64]);
    gll16(vg0 + (size_t)kt * 64,            &Vs[buf][r0 * 64]);
    gll16(vg0 + (size_t)kt * 64 + 8 * TT,   &Vs[buf][(r0 + 8) * 64]);
  };

  auto qk = [&](const short* Kc, f32x16& t0, f32x16& t1) {
    f32x16 a = {}, b = {};
    __builtin_amdgcn_s_setprio(1);
#pragma unroll
    for (int ds = 0; ds < 4; ++ds) {
      const int cb = ds * 32 + g * 16;
      const bf16x8 ka0 = lds16(Kc, l31, cb);
      const bf16x8 ka1 = lds16(Kc, 32 + l31, cb);
      a = __builtin_amdgcn_mfma_f32_32x32x16_bf16(ka0, qf[ds], a, 0, 0, 0);
      b = __builtin_amdgcn_mfma_f32_32x32x16_bf16(ka1, qf[ds], b, 0, 0, 0);
    }
    __builtin_amdgcn_s_setprio(0);
    t0 = a; t1 = b;
  };

  // softmax-finish + PV for tile j with raw scores (s0,s1), V in Vc
  auto smpv = [&](int j, f32x16& s0, f32x16& s1, const short* Vc) {
    if (masked) {
#pragma unroll
      for (int r = 0; r < 16; ++r) {
        const int kk = (r & 3) + 8 * (r >> 2) + 4 * g;
        if (maskb[j * 64 + kk]) s0[r] += -1e30f;
        if (maskb[j * 64 + 32 + kk]) s1[r] += -1e30f;
      }
    }
    // row max over 64 keys: max3 tree + cross-half
    float b8[8];
#pragma unroll
    for (int i = 0; i < 8; ++i) b8[i] = max3f(s0[i], s0[i + 8], s1[i]);
    float c4[4];
#pragma unroll
    for (int i = 0; i < 4; ++i) c4[i] = fmaxf(s1[8 + i], s1[12 + i]);
    const float d0 = max3f(b8[0], b8[1], b8[2]);
    const float d1 = max3f(b8[3], b8[4], b8[5]);
    const float d2 = max3f(b8[6], b8[7], c4[0]);
    const float d3 = max3f(c4[1], c4[2], c4[3]);
    const float mx = fmaxf(max3f(d0, d1, d2), d3);
    const float pmax = fmaxf(mx, __shfl_xor(mx, 32));

    if (j == 0) {
      m_run = pmax;
    } else if (!__all((int)(pmax - m_run <= 8.0f))) {
      const float nm = fmaxf(m_run, pmax);
      const float sc = ex2(m_run - nm);
      m_run = nm;
      l_run *= sc;
      if (lane < 32) psc[wave][l31] = sc;
      asm volatile("s_waitcnt lgkmcnt(0)" ::: "memory");
      __builtin_amdgcn_sched_barrier(0);
#pragma unroll
      for (int r = 0; r < 16; ++r) {
        const float s = psc[wave][(r & 3) + 8 * (r >> 2) + 4 * g];
        oa0[r] *= s; oa1[r] *= s;
      }
    }

    // P = exp2(S - m) in place
#pragma unroll
    for (int i = 0; i < 16; ++i) { s0[i] = ex2(s0[i] - m_run); s1[i] = ex2(s1[i] - m_run); }

    // row sum (pairwise tree)
    float a8[8];
#pragma unroll
    for (int i = 0; i < 8; ++i) a8[i] = (s0[i] + s0[i + 8]) + (s1[i] + s1[i + 8]);
    const float e0 = (a8[0] + a8[1]) + (a8[2] + a8[3]);
    const float e1 = (a8[4] + a8[5]) + (a8[6] + a8[7]);
    const float rsum = e0 + e1;
    l_run += rsum + __shfl_xor(rsum, 32);

    // P -> bf16 A-frags, convert-and-consume to cap register pressure
    bf16x8 f0, f1;
    __builtin_amdgcn_s_setprio(1);
    p_to_frags(s0, hi, &f0, &f1);
    {
      const int cb0 = 0 * 32 + g * 16, cb1 = 1 * 32 + g * 16;
      oa0 = __builtin_amdgcn_mfma_f32_32x32x16_bf16(f0, lds16(Vc, l31, cb0), oa0, 0, 0, 0);
      oa1 = __builtin_amdgcn_mfma_f32_32x32x16_bf16(f0, lds16(Vc, 32 + l31, cb0), oa1, 0, 0, 0);
      oa0 = __builtin_amdgcn_mfma_f32_32x32x16_bf16(f1, lds16(Vc, l31, cb1), oa0, 0, 0, 0);
      oa1 = __builtin_amdgcn_mfma_f32_32x32x16_bf16(f1, lds16(Vc, 32 + l31, cb1), oa1, 0, 0, 0);
    }
    p_to_frags(s1, hi, &f0, &f1);
    {
      const int cb2 = 2 * 32 + g * 16, cb3 = 3 * 32 + g * 16;
      oa0 = __builtin_amdgcn_mfma_f32_32x32x16_bf16(f0, lds16(Vc, l31, cb2), oa0, 0, 0, 0);
      oa1 = __builtin_amdgcn_mfma_f32_32x32x16_bf16(f0, lds16(Vc, 32 + l31, cb2), oa1, 0, 0, 0);
      oa0 = __builtin_amdgcn_mfma_f32_32x32x16_bf16(f1, lds16(Vc, l31, cb3), oa0, 0, 0, 0);
      oa1 = __builtin_amdgcn_mfma_f32_32x32x16_bf16(f1, lds16(Vc, 32 + l31, cb3), oa1, 0, 0, 0);
    }
    __builtin_amdgcn_s_setprio(0);
  };

  f32x16 sA0, sA1, sB0, sB1;

  // prime: stage(0)->buf0; barrier; stage(1)->buf1; QK(0); barrier
  stage(0, 0);
  __syncthreads();
  stage(1, 1);
  qk(Ks[0], sA0, sA1);
  __syncthreads();

  for (int kt = 1; kt < TT / 64; ++kt) {
    const int bi = kt % 3, pv = (kt - 1) % 3, nx = (kt + 1) % 3;
    if (kt + 1 < TT / 64) stage(kt + 1, nx);
    if (kt & 1) { qk(Ks[bi], sB0, sB1); smpv(kt - 1, sA0, sA1, Vs[pv]); }
    else        { qk(Ks[bi], sA0, sA1); smpv(kt - 1, sB0, sB1, Vs[pv]); }
    __syncthreads();
  }
  // tail: TT/64-1 = 31 (odd) -> last QK wrote sB
  smpv(TT / 64 - 1, sB0, sB1, Vs[(TT / 64 - 1) % 3]);

  // epilogue: O[q][d] / l
  const float linv = 1.0f / l_run;  // valid for q = l31
#pragma unroll
  for (int r = 0; r < 16; ++r) {
    const int qr = (r & 3) + 8 * (r >> 2) + 4 * g;
    const float lv = __shfl(linv, (lane & 32) | qr, 64);
    const int trow = q0 + qr;
    const size_t orow = ((size_t)bb * TT + trow) * 512 + hh * 64 + l31;
    o[orow]      = f2b(oa0[r] * lv);
    o[orow + 32] = f2b(oa1[r] * lv);
  }
}

extern "C" void kernel_launch(void* const* d_in, const int* in_sizes, int n_in,
                              void* d_out, int out_size, void* d_ws, size_t ws_size,
                              hipStream_t stream) {
  (void)in_sizes; (void)n_in; (void)out_size; (void)ws_size;
  const float* x = (const float*)d_in[0];
  const unsigned char* mask = (const unsigned char*)d_in[1];
  const float* ln_w = (const float*)d_in[2];
  const float* ln_b = (const float*)d_in[3];
  const float* w_qkv = (const float*)d_in[4];
  const float* b_qkv = (const float*)d_in[5];
  const float* w_o = (const float*)d_in[6];
  const float* b_o = (const float*)d_in[7];
  float* out = (float*)d_out;

  char* ws = (char*)d_ws;
  short* h_buf = (short*)(ws);                 // 16384*512 bf16 = 16 MB; reused as attn_out
  short* wqkvT = (short*)(ws + 16777216);      // 1536*512 bf16
  short* woT   = (short*)(ws + 18350080);      // 512*512 bf16
  short* q_ws  = (short*)(ws + 18874368);      // [64][2048][64] bf16
  short* k_ws  = (short*)(ws + 35651584);      // [64][2048][64] bf16
  short* vt_ws = (short*)(ws + 52428800);      // [64][64][2048] bf16
  float2* tab  = (float2*)(ws + 69206016);     // [2048][32] float2 = 512 KB

  hipLaunchKernelGGL(prep_kernel, dim3(512), dim3(256), 0, stream,
                     w_qkv, wqkvT, w_o, woT, tab);
  hipLaunchKernelGGL(ln_kernel, dim3(16384), dim3(256), 0, stream, x, ln_w, ln_b, h_buf);
  hipLaunchKernelGGL((gemm128_kernel<0>), dim3(128, 12), dim3(256), 0, stream,
                     h_buf, wqkvT, b_qkv, tab, (void*)q_ws, (void*)k_ws, (void*)vt_ws);
  hipLaunchKernelGGL(attn_kernel, dim3(1024), dim3(256), 0, stream,
                     q_ws, k_ws, vt_ws, mask, h_buf);
  hipLaunchKernelGGL((gemm128_kernel<1>), dim3(128, 4), dim3(256), 0, stream,
                     h_buf, woT, b_o, tab, (void*)out, nullptr, nullptr);
}

// Round 9
// 201.461 us; speedup vs baseline: 1.5676x; 1.5676x over previous
//
#include <hip/hip_runtime.h>
#include <hip/hip_bf16.h>

#define TT 2048

typedef __attribute__((ext_vector_type(8))) short bf16x8;
typedef __attribute__((ext_vector_type(4))) float f32x4;
typedef __attribute__((ext_vector_type(16))) float f32x16;
typedef __attribute__((ext_vector_type(2))) int i32x2;

__device__ __forceinline__ short f2b(float f) {
  union { float f; unsigned u; } a; a.f = f;
  unsigned r = a.u + 0x7fffu + ((a.u >> 16) & 1u);
  return (short)(r >> 16);
}
__device__ __forceinline__ unsigned cvtpk(float lo, float hi) {
  unsigned r;
  asm("v_cvt_pk_bf16_f32 %0, %1, %2" : "=v"(r) : "v"(lo), "v"(hi));
  return r;
}
__device__ __forceinline__ float max3f(float a, float b, float c) {
  float d;
  asm("v_max3_f32 %0, %1, %2, %3" : "=v"(d) : "v"(a), "v"(b), "v"(c));
  return d;
}
__device__ __forceinline__ float ex2(float x) {
#if __has_builtin(__builtin_amdgcn_exp2f)
  return __builtin_amdgcn_exp2f(x);
#else
  return exp2f(x);
#endif
}
// async global->LDS, 16B per lane; lds dest = wave-uniform base + lane*16
__device__ __forceinline__ void gll16(const void* g, void* l) {
  __builtin_amdgcn_global_load_lds(
      (const __attribute__((address_space(1))) unsigned int*)g,
      (__attribute__((address_space(3))) unsigned int*)l, 16, 0, 0);
}
// exchange high-32 lanes of a with low-32 lanes of b
__device__ __forceinline__ void swap_halves(unsigned &a, unsigned &b, bool hi) {
#if __has_builtin(__builtin_amdgcn_permlane32_swap)
  i32x2 r = __builtin_amdgcn_permlane32_swap((int)a, (int)b, false, false);
  a = (unsigned)r[0]; b = (unsigned)r[1];
#else
  unsigned as = (unsigned)__shfl_xor((int)a, 32);
  unsigned bs = (unsigned)__shfl_xor((int)b, 32);
  unsigned na = hi ? bs : a;
  unsigned nb = hi ? b : as;
  a = na; b = nb;
#endif
}

// 16 f32 P-values -> two PV A-frags (keys 0..15 and 16..31 of a 32-key tile)
__device__ __forceinline__ void p_to_frags(const f32x16 p, bool hi, bf16x8* f0, bf16x8* f1) {
  unsigned A[4][2];
#pragma unroll
  for (int u = 0; u < 4; ++u)
#pragma unroll
    for (int c = 0; c < 2; ++c)
      A[u][c] = cvtpk(p[4 * u + 2 * c], p[4 * u + 2 * c + 1]);
  swap_halves(A[0][0], A[1][0], hi);
  swap_halves(A[0][1], A[1][1], hi);
  swap_halves(A[2][0], A[3][0], hi);
  swap_halves(A[2][1], A[3][1], hi);
  union { unsigned u[4]; bf16x8 v; } r0, r1;
  r0.u[0] = A[0][0]; r0.u[1] = A[0][1]; r0.u[2] = A[1][0]; r0.u[3] = A[1][1];
  r1.u[0] = A[2][0]; r1.u[1] = A[2][1]; r1.u[2] = A[3][0]; r1.u[3] = A[3][1];
  *f0 = r0.v; *f1 = r1.v;
}

// swizzled LDS access, 128B rows: byte col ^ ((row&7)<<4)
__device__ __forceinline__ bf16x8 lds16(const short* base, int row, int cb) {
  return *reinterpret_cast<const bf16x8*>(
      reinterpret_cast<const char*>(base) + row * 128 + (cb ^ ((row & 7) << 4)));
}

// fused prep: transpose-cast w_qkv (192 blocks) + w_o (64 blocks) + RoPE table (256)
__global__ __launch_bounds__(256) void prep_kernel(const float* __restrict__ w_qkv,
                                                   short* __restrict__ wqkvT,
                                                   const float* __restrict__ w_o,
                                                   short* __restrict__ woT,
                                                   float2* __restrict__ tab) {
  __shared__ float t[64][65];
  const int id = blockIdx.x;
  if (id < 256) {
    const float* src; short* dst; int N, n0, k0;
    if (id < 192) { src = w_qkv; dst = wqkvT; N = 1536; n0 = (id % 24) * 64; k0 = (id / 24) * 64; }
    else { const int i2 = id - 192; src = w_o; dst = woT; N = 512; n0 = (i2 & 7) * 64; k0 = (i2 >> 3) * 64; }
    const int c = threadIdx.x & 63, r4 = threadIdx.x >> 6;
#pragma unroll
    for (int i = 0; i < 16; ++i) {
      const int r = i * 4 + r4;
      t[r][c] = src[(size_t)(k0 + r) * N + n0 + c];
    }
    __syncthreads();
#pragma unroll
    for (int i = 0; i < 16; ++i) {
      const int r = i * 4 + r4;
      dst[(size_t)(n0 + r) * 512 + k0 + c] = f2b(t[c][r]);
    }
  } else {
    const int idx = (id - 256) * 256 + threadIdx.x;  // 65536
    const int i = idx & 31, tt = idx >> 5;
    const float inv_freq = __expf(-(float)i * (9.210340371976184f / 32.0f));
    float sv, cv;
    sincosf((float)tt * inv_freq, &sv, &cv);
    tab[idx] = make_float2(cv, sv);
  }
}

// LayerNorm rows of 512, fp32 in, bf16 out
__global__ __launch_bounds__(256) void ln_kernel(const float* __restrict__ x,
                                                 const float* __restrict__ w,
                                                 const float* __restrict__ b,
                                                 short* __restrict__ h) {
  const int row = blockIdx.x;
  const int tid = threadIdx.x;
  const float2 v = *reinterpret_cast<const float2*>(x + (size_t)row * 512 + tid * 2);
  float s = v.x + v.y;
  float sq = v.x * v.x + v.y * v.y;
  for (int off = 1; off < 64; off <<= 1) { s += __shfl_xor(s, off); sq += __shfl_xor(sq, off); }
  __shared__ float red[8];
  const int wv = tid >> 6;
  if ((tid & 63) == 0) { red[wv] = s; red[wv + 4] = sq; }
  __syncthreads();
  s = red[0] + red[1] + red[2] + red[3];
  sq = red[4] + red[5] + red[6] + red[7];
  const float mu = s * (1.0f / 512.0f);
  const float var = sq * (1.0f / 512.0f) - mu * mu;
  const float inv = rsqrtf(var + 1e-5f);
  const float2 wv2 = *reinterpret_cast<const float2*>(w + tid * 2);
  const float2 bv2 = *reinterpret_cast<const float2*>(b + tid * 2);
  const float h0 = (v.x - mu) * inv * wv2.x + bv2.x;
  const float h1 = (v.y - mu) * inv * wv2.y + bv2.y;
  unsigned u = (unsigned)(unsigned short)f2b(h0) | ((unsigned)(unsigned short)f2b(h1) << 16);
  *reinterpret_cast<unsigned*>(h + (size_t)row * 512 + tid * 2) = u;
}

// 128x128 tile GEMM via global_load_lds, both-sides-swizzled LDS [128][64].
template <int EPI>
__global__ __launch_bounds__(256) void gemm128_kernel(const short* __restrict__ A,
                                                      const short* __restrict__ Bt,
                                                      const float* __restrict__ bias,
                                                      const float2* __restrict__ tab,
                                                      void* __restrict__ o0,
                                                      void* __restrict__ o1,
                                                      void* __restrict__ o2) {
  __shared__ short As[128 * 64];
  __shared__ short Bs[128 * 64];
  const int tid = threadIdx.x;
  const int lane = tid & 63, wave = tid >> 6;
  const int lr = lane & 15, lg = lane >> 4;
  const int wm = wave >> 1, wn = wave & 1;
  const int m0 = blockIdx.x * 128, n0 = blockIdx.y * 128;

  const int swz_col = ((lane & 7) ^ ((lane >> 3) & 7)) * 8;
  const short* Ag = A + (size_t)(m0 + wave * 32 + (lane >> 3)) * 512 + swz_col;
  const short* Bg = Bt + (size_t)(n0 + wave * 32 + (lane >> 3)) * 512 + swz_col;
  short* AsW = &As[(wave * 32) * 64];
  short* BsW = &Bs[(wave * 32) * 64];

  f32x4 acc[4][4] = {};

  for (int k0 = 0; k0 < 512; k0 += 64) {
#pragma unroll
    for (int i = 0; i < 4; ++i) {
      gll16(Ag + (size_t)i * 8 * 512 + k0, AsW + i * 8 * 64);
      gll16(Bg + (size_t)i * 8 * 512 + k0, BsW + i * 8 * 64);
    }
    __syncthreads();
#pragma unroll
    for (int ks = 0; ks < 2; ++ks) {
      bf16x8 af[4], bfr[4];
#pragma unroll
      for (int m = 0; m < 4; ++m)
        af[m] = lds16(As, wm * 64 + m * 16 + lr, ks * 64 + lg * 16);
#pragma unroll
      for (int n = 0; n < 4; ++n)
        bfr[n] = lds16(Bs, wn * 64 + n * 16 + lr, ks * 64 + lg * 16);
#pragma unroll
      for (int m = 0; m < 4; ++m)
#pragma unroll
        for (int n = 0; n < 4; ++n)
          acc[m][n] = __builtin_amdgcn_mfma_f32_16x16x32_bf16(af[m], bfr[n], acc[m][n], 0, 0, 0);
    }
    __syncthreads();
  }

  if (EPI == 0) {
    const int base = n0 + wn * 64;             // wave-uniform head window
    const int which = base >> 9;               // 0=q 1=k 2=v
    const int hh = (base & 511) >> 6;
    short* qp = (short*)o0; short* kp = (short*)o1; short* vtp = (short*)o2;
    const float b0 = bias[base + lr], b1 = bias[base + 16 + lr];
    const float b2 = bias[base + 32 + lr], b3 = bias[base + 48 + lr];
    const float QS = 0.125f * 1.4426950408889634f;  // 1/sqrt(dk) * log2(e), q only
#pragma unroll
    for (int m = 0; m < 4; ++m) {
      const int rowb = m0 + wm * 64 + m * 16 + lg * 4;
#pragma unroll
      for (int j = 0; j < 4; ++j) {
        const int t = (rowb + j) & 2047;
        const int bh = ((rowb + j) >> 11) * 8 + hh;
        float v0 = acc[m][0][j] + b0;
        float v1 = acc[m][1][j] + b1;
        float v2 = acc[m][2][j] + b2;
        float v3 = acc[m][3][j] + b3;
        if (which < 2) {
          const float2 cs0 = tab[t * 32 + lr];
          const float2 cs1 = tab[t * 32 + 16 + lr];
          float r0 = v0 * cs0.x - v2 * cs0.y;
          float r2 = v2 * cs0.x + v0 * cs0.y;
          float r1 = v1 * cs1.x - v3 * cs1.y;
          float r3 = v3 * cs1.x + v1 * cs1.y;
          if (which == 0) { r0 *= QS; r1 *= QS; r2 *= QS; r3 *= QS; }
          short* dst = (which == 0 ? qp : kp) + ((size_t)bh * TT + t) * 64;
          dst[lr] = f2b(r0); dst[16 + lr] = f2b(r1);
          dst[32 + lr] = f2b(r2); dst[48 + lr] = f2b(r3);
        } else {
          short* vb = vtp + (size_t)bh * 64 * TT + t;
          vb[(size_t)lr * TT] = f2b(v0);
          vb[(size_t)(16 + lr) * TT] = f2b(v1);
          vb[(size_t)(32 + lr) * TT] = f2b(v2);
          vb[(size_t)(48 + lr) * TT] = f2b(v3);
        }
      }
    }
  } else {
#pragma unroll
    for (int m = 0; m < 4; ++m)
#pragma unroll
      for (int n = 0; n < 4; ++n)
#pragma unroll
        for (int j = 0; j < 4; ++j) {
          const int row = m0 + wm * 64 + m * 16 + lg * 4 + j;
          const int col = n0 + wn * 64 + n * 16 + lr;
          ((float*)o0)[(size_t)row * 512 + col] = acc[m][n][j] + bias[col];
        }
  }
}

// Flash attention, in-block split-K: 8 waves = 2 streams x 4 waves.
// Stream 0: keys [0,1024); stream 1: keys [1024,2048). Both cover the same
// 128 q-rows (wave w and w+4 share q). KVBLK=32, double-buffered gll staging.
// Flash-combine of the two streams through LDS at the end.
// grid: 1024 blocks (XCD-swizzled) x 512 threads.
__global__ __launch_bounds__(512) void attn_kernel(const short* __restrict__ q,
                                                   const short* __restrict__ k,
                                                   const short* __restrict__ vt,
                                                   const unsigned char* __restrict__ mask,
                                                   short* __restrict__ o) {
  __shared__ short KVs[2][2][2][32 * 64];  // [K/V][stream][buf][32 rows x 128B]
  __shared__ float psc[8][32];
  __shared__ float mls[8][32][2];
  __shared__ float linvs[4][32];
  float* Oex = (float*)&KVs[0][0][0][0];   // combine overlay: [pair][32 q][64 d] f32 = 32KB

  const int tid = threadIdx.x;
  const int lane = tid & 63, wave = tid >> 6;   // 0..7
  const int grp = wave >> 2, wl = wave & 3;     // stream, wave-in-stream
  const int l31 = lane & 31, g = lane >> 5;
  const bool hi = (g != 0);
  // bijective XCD swizzle: 1024 blocks, 8 XCDs
  const int nb = (blockIdx.x & 7) * 128 + (blockIdx.x >> 3);
  const int bh = nb >> 4, qt = nb & 15;
  const int bb = bh >> 3, hh = bh & 7;
  const int q0 = qt * 128 + wl * 32;
  const size_t bhT = (size_t)bh * TT;
  const unsigned char* maskb = mask + (size_t)bb * TT;
  const int kbase = grp * 1024;

  // whole-row mask flag (hoisted)
  unsigned mor = 0;
  const unsigned* mw = (const unsigned*)maskb;
#pragma unroll
  for (int i = 0; i < 8; ++i) mor |= mw[lane + 64 * i];
  const bool masked = __any((int)(mor != 0));

  // Q as B-operand frags (both streams load the same q rows)
  bf16x8 qf[4];
#pragma unroll
  for (int ds = 0; ds < 4; ++ds)
    qf[ds] = *reinterpret_cast<const bf16x8*>(q + (bhT + q0 + l31) * 64 + ds * 16 + g * 8);

  f32x16 oa0 = {}, oa1 = {};
  float m_run = 0.0f, l_run = 0.0f;

  // --- staging addresses ---
  // K tile: [32 keys][128B]; wl stages rows [wl*8, wl*8+8): 1 gll
  const int swzk = ((lane & 7) ^ (lane >> 3)) * 8;
  const short* kg0 = k + (bhT + kbase + wl * 8 + (lane >> 3)) * 64 + swzk;
  // V tile: [32 rows][128B]: row r col<64 = V^T[d=r][keys], col>=64 = V^T[d=r+32][keys]
  // per-lane inverse-swizzled source decomposition (rule #21)
  const int Rv = lane >> 3;
  const int lcol = ((lane & 7) * 16) ^ (Rv << 4);
  const int dv = wl * 8 + Rv + ((lcol & 64) ? 32 : 0);
  const int kbv = (lcol & 63) >> 1;
  const short* vg0 = vt + ((size_t)bh * 64 + dv) * TT + kbase + kbv;

  short* Kst[2] = { &KVs[0][grp][0][0], &KVs[0][grp][1][0] };
  short* Vst[2] = { &KVs[1][grp][0][0], &KVs[1][grp][1][0] };

  // prologue: stage tile 0
  gll16(kg0, Kst[0] + wl * 512);
  gll16(vg0, Vst[0] + wl * 512);
  __syncthreads();

  for (int kt = 0; kt < 32; ++kt) {
    const int cur = kt & 1;
    if (kt < 31) {
      gll16(kg0 + (size_t)(kt + 1) * 2048, Kst[cur ^ 1] + wl * 512);
      gll16(vg0 + (size_t)(kt + 1) * 32,   Vst[cur ^ 1] + wl * 512);
    }
    const short* Kc = Kst[cur];
    const short* Vc = Vst[cur];

    // S^T = K Q^T : 32 keys x 32 q
    f32x16 s0 = {};
    __builtin_amdgcn_s_setprio(1);
#pragma unroll
    for (int ds = 0; ds < 4; ++ds)
      s0 = __builtin_amdgcn_mfma_f32_32x32x16_bf16(lds16(Kc, l31, ds * 32 + g * 16),
                                                   qf[ds], s0, 0, 0, 0);
    __builtin_amdgcn_s_setprio(0);

    if (masked) {
#pragma unroll
      for (int r = 0; r < 16; ++r) {
        const int kk = kbase + kt * 32 + (r & 3) + 8 * (r >> 2) + 4 * g;
        if (maskb[kk]) s0[r] += -1e30f;
      }
    }

    // row max over 32 keys: in-lane tree + cross-half
    float b8[8];
#pragma unroll
    for (int i = 0; i < 8; ++i) b8[i] = fmaxf(s0[i], s0[i + 8]);
    const float e0 = max3f(b8[0], b8[1], b8[2]);
    const float e1 = max3f(b8[3], b8[4], b8[5]);
    const float e2 = fmaxf(b8[6], b8[7]);
    const float mx = max3f(e0, e1, e2);
    const float pmax = fmaxf(mx, __shfl_xor(mx, 32));

    if (kt == 0) {
      m_run = pmax;
    } else if (!__all((int)(pmax - m_run <= 8.0f))) {
      const float nm = fmaxf(m_run, pmax);
      const float sc = ex2(m_run - nm);
      m_run = nm;
      l_run *= sc;
      if (lane < 32) psc[wave][l31] = sc;
      asm volatile("s_waitcnt lgkmcnt(0)" ::: "memory");
#pragma unroll
      for (int r = 0; r < 16; ++r) {
        const float s = psc[wave][(r & 3) + 8 * (r >> 2) + 4 * g];
        oa0[r] *= s; oa1[r] *= s;
      }
    }

    // P = exp2(S - m)
#pragma unroll
    for (int i = 0; i < 16; ++i) s0[i] = ex2(s0[i] - m_run);

    // row sum
    float a8[8];
#pragma unroll
    for (int i = 0; i < 8; ++i) a8[i] = s0[i] + s0[i + 8];
    const float t0 = (a8[0] + a8[1]) + (a8[2] + a8[3]);
    const float t1 = (a8[4] + a8[5]) + (a8[6] + a8[7]);
    const float rsum = t0 + t1;
    l_run += rsum + __shfl_xor(rsum, 32);

    // P -> bf16 A-frags; PV (4 MFMA)
    bf16x8 f0, f1;
    p_to_frags(s0, hi, &f0, &f1);
    __builtin_amdgcn_s_setprio(1);
    oa0 = __builtin_amdgcn_mfma_f32_32x32x16_bf16(f0, lds16(Vc, l31, g * 16), oa0, 0, 0, 0);
    oa1 = __builtin_amdgcn_mfma_f32_32x32x16_bf16(f0, lds16(Vc, l31, 64 + g * 16), oa1, 0, 0, 0);
    oa0 = __builtin_amdgcn_mfma_f32_32x32x16_bf16(f1, lds16(Vc, l31, 32 + g * 16), oa0, 0, 0, 0);
    oa1 = __builtin_amdgcn_mfma_f32_32x32x16_bf16(f1, lds16(Vc, l31, 96 + g * 16), oa1, 0, 0, 0);
    __builtin_amdgcn_s_setprio(0);

    __syncthreads();
  }

  // ---- flash-combine of the two streams (pair = wave w & w+4) ----
  if (lane < 32) { mls[wave][l31][0] = m_run; mls[wave][l31][1] = l_run; }
  __syncthreads();

  const int pw = wave & 3;
  const float mA = mls[pw][l31][0],     lA = mls[pw][l31][1];
  const float mB = mls[pw + 4][l31][0], lB = mls[pw + 4][l31][1];
  const float mC = fmaxf(mA, mB);
  const float sA = ex2(mA - mC), sB = ex2(mB - mC);
  if (lane < 32) {
    psc[wave][l31] = (grp == 0) ? sA : sB;
    if (grp == 0) linvs[pw][l31] = 1.0f / (sA * lA + sB * lB);
  }
  asm volatile("s_waitcnt lgkmcnt(0)" ::: "memory");
  // scale own partial O by per-q scale (broadcast via LDS)
#pragma unroll
  for (int r = 0; r < 16; ++r) {
    const float s = psc[wave][(r & 3) + 8 * (r >> 2) + 4 * g];
    oa0[r] *= s; oa1[r] *= s;
  }
  __syncthreads();  // all K/V reads done; safe to overlay Oex

  if (grp == 1) {
#pragma unroll
    for (int r = 0; r < 16; ++r) {
      const int qr = (r & 3) + 8 * (r >> 2) + 4 * g;
      Oex[(pw * 32 + qr) * 64 + l31] = oa0[r];
      Oex[(pw * 32 + qr) * 64 + 32 + l31] = oa1[r];
    }
  }
  __syncthreads();

  if (grp == 0) {
#pragma unroll
    for (int r = 0; r < 16; ++r) {
      const int qr = (r & 3) + 8 * (r >> 2) + 4 * g;
      const float v0 = oa0[r] + Oex[(pw * 32 + qr) * 64 + l31];
      const float v1 = oa1[r] + Oex[(pw * 32 + qr) * 64 + 32 + l31];
      const float lv = linvs[pw][qr];
      const int trow = q0 + qr;
      const size_t orow = ((size_t)bb * TT + trow) * 512 + hh * 64 + l31;
      o[orow]      = f2b(v0 * lv);
      o[orow + 32] = f2b(v1 * lv);
    }
  }
}

extern "C" void kernel_launch(void* const* d_in, const int* in_sizes, int n_in,
                              void* d_out, int out_size, void* d_ws, size_t ws_size,
                              hipStream_t stream) {
  (void)in_sizes; (void)n_in; (void)out_size; (void)ws_size;
  const float* x = (const float*)d_in[0];
  const unsigned char* mask = (const unsigned char*)d_in[1];
  const float* ln_w = (const float*)d_in[2];
  const float* ln_b = (const float*)d_in[3];
  const float* w_qkv = (const float*)d_in[4];
  const float* b_qkv = (const float*)d_in[5];
  const float* w_o = (const float*)d_in[6];
  const float* b_o = (const float*)d_in[7];
  float* out = (float*)d_out;

  char* ws = (char*)d_ws;
  short* h_buf = (short*)(ws);                 // 16384*512 bf16 = 16 MB; reused as attn_out
  short* wqkvT = (short*)(ws + 16777216);      // 1536*512 bf16
  short* woT   = (short*)(ws + 18350080);      // 512*512 bf16
  short* q_ws  = (short*)(ws + 18874368);      // [64][2048][64] bf16
  short* k_ws  = (short*)(ws + 35651584);      // [64][2048][64] bf16
  short* vt_ws = (short*)(ws + 52428800);      // [64][64][2048] bf16
  float2* tab  = (float2*)(ws + 69206016);     // [2048][32] float2 = 512 KB

  hipLaunchKernelGGL(prep_kernel, dim3(512), dim3(256), 0, stream,
                     w_qkv, wqkvT, w_o, woT, tab);
  hipLaunchKernelGGL(ln_kernel, dim3(16384), dim3(256), 0, stream, x, ln_w, ln_b, h_buf);
  hipLaunchKernelGGL((gemm128_kernel<0>), dim3(128, 12), dim3(256), 0, stream,
                     h_buf, wqkvT, b_qkv, tab, (void*)q_ws, (void*)k_ws, (void*)vt_ws);
  hipLaunchKernelGGL(attn_kernel, dim3(1024), dim3(512), 0, stream,
                     q_ws, k_ws, vt_ws, mask, h_buf);
  hipLaunchKernelGGL((gemm128_kernel<1>), dim3(128, 4), dim3(256), 0, stream,
                     h_buf, woT, b_o, tab, (void*)out, nullptr, nullptr);
}

// Round 10
// 175.230 us; speedup vs baseline: 1.8022x; 1.1497x over previous
//
#include <hip/hip_runtime.h>
#include <hip/hip_bf16.h>

#define TT 2048

typedef __attribute__((ext_vector_type(8))) short bf16x8;
typedef __attribute__((ext_vector_type(4))) float f32x4;
typedef __attribute__((ext_vector_type(16))) float f32x16;
typedef __attribute__((ext_vector_type(2))) int i32x2;

__device__ __forceinline__ short f2b(float f) {
  union { float f; unsigned u; } a; a.f = f;
  unsigned r = a.u + 0x7fffu + ((a.u >> 16) & 1u);
  return (short)(r >> 16);
}
__device__ __forceinline__ unsigned cvtpk(float lo, float hi) {
  unsigned r;
  asm("v_cvt_pk_bf16_f32 %0, %1, %2" : "=v"(r) : "v"(lo), "v"(hi));
  return r;
}
__device__ __forceinline__ float max3f(float a, float b, float c) {
  float d;
  asm("v_max3_f32 %0, %1, %2, %3" : "=v"(d) : "v"(a), "v"(b), "v"(c));
  return d;
}
__device__ __forceinline__ float ex2(float x) {
#if __has_builtin(__builtin_amdgcn_exp2f)
  return __builtin_amdgcn_exp2f(x);
#else
  return exp2f(x);
#endif
}
// async global->LDS, 16B per lane; lds dest = wave-uniform base + lane*16
__device__ __forceinline__ void gll16(const void* g, void* l) {
  __builtin_amdgcn_global_load_lds(
      (const __attribute__((address_space(1))) unsigned int*)g,
      (__attribute__((address_space(3))) unsigned int*)l, 16, 0, 0);
}
// exchange high-32 lanes of a with low-32 lanes of b
__device__ __forceinline__ void swap_halves(unsigned &a, unsigned &b, bool hi) {
#if __has_builtin(__builtin_amdgcn_permlane32_swap)
  i32x2 r = __builtin_amdgcn_permlane32_swap((int)a, (int)b, false, false);
  a = (unsigned)r[0]; b = (unsigned)r[1];
#else
  unsigned as = (unsigned)__shfl_xor((int)a, 32);
  unsigned bs = (unsigned)__shfl_xor((int)b, 32);
  unsigned na = hi ? bs : a;
  unsigned nb = hi ? b : as;
  a = na; b = nb;
#endif
}

// 16 f32 P-values (one 32-row S^T fragment) -> two PV A-frags
__device__ __forceinline__ void p_to_frags(const f32x16 p, bool hi, bf16x8* f0, bf16x8* f1) {
  unsigned A[4][2];
#pragma unroll
  for (int u = 0; u < 4; ++u)
#pragma unroll
    for (int c = 0; c < 2; ++c)
      A[u][c] = cvtpk(p[4 * u + 2 * c], p[4 * u + 2 * c + 1]);
  swap_halves(A[0][0], A[1][0], hi);
  swap_halves(A[0][1], A[1][1], hi);
  swap_halves(A[2][0], A[3][0], hi);
  swap_halves(A[2][1], A[3][1], hi);
  union { unsigned u[4]; bf16x8 v; } r0, r1;
  r0.u[0] = A[0][0]; r0.u[1] = A[0][1]; r0.u[2] = A[1][0]; r0.u[3] = A[1][1];
  r1.u[0] = A[2][0]; r1.u[1] = A[2][1]; r1.u[2] = A[3][0]; r1.u[3] = A[3][1];
  *f0 = r0.v; *f1 = r1.v;
}

// swizzled LDS access, 128B rows: byte col ^ ((row&7)<<4)
__device__ __forceinline__ bf16x8 lds16(const short* base, int row, int cb) {
  return *reinterpret_cast<const bf16x8*>(
      reinterpret_cast<const char*>(base) + row * 128 + (cb ^ ((row & 7) << 4)));
}

// fused prep: transpose-cast w_qkv (192 blocks) + w_o (64 blocks) + RoPE table (256)
__global__ __launch_bounds__(256) void prep_kernel(const float* __restrict__ w_qkv,
                                                   short* __restrict__ wqkvT,
                                                   const float* __restrict__ w_o,
                                                   short* __restrict__ woT,
                                                   float2* __restrict__ tab) {
  __shared__ float t[64][65];
  const int id = blockIdx.x;
  if (id < 256) {
    const float* src; short* dst; int N, n0, k0;
    if (id < 192) { src = w_qkv; dst = wqkvT; N = 1536; n0 = (id % 24) * 64; k0 = (id / 24) * 64; }
    else { const int i2 = id - 192; src = w_o; dst = woT; N = 512; n0 = (i2 & 7) * 64; k0 = (i2 >> 3) * 64; }
    const int c = threadIdx.x & 63, r4 = threadIdx.x >> 6;
#pragma unroll
    for (int i = 0; i < 16; ++i) {
      const int r = i * 4 + r4;
      t[r][c] = src[(size_t)(k0 + r) * N + n0 + c];
    }
    __syncthreads();
#pragma unroll
    for (int i = 0; i < 16; ++i) {
      const int r = i * 4 + r4;
      dst[(size_t)(n0 + r) * 512 + k0 + c] = f2b(t[c][r]);
    }
  } else {
    const int idx = (id - 256) * 256 + threadIdx.x;  // 65536
    const int i = idx & 31, tt = idx >> 5;
    const float inv_freq = __expf(-(float)i * (9.210340371976184f / 32.0f));
    float sv, cv;
    sincosf((float)tt * inv_freq, &sv, &cv);
    tab[idx] = make_float2(cv, sv);
  }
}

// LayerNorm rows of 512, fp32 in, bf16 out
__global__ __launch_bounds__(256) void ln_kernel(const float* __restrict__ x,
                                                 const float* __restrict__ w,
                                                 const float* __restrict__ b,
                                                 short* __restrict__ h) {
  const int row = blockIdx.x;
  const int tid = threadIdx.x;
  const float2 v = *reinterpret_cast<const float2*>(x + (size_t)row * 512 + tid * 2);
  float s = v.x + v.y;
  float sq = v.x * v.x + v.y * v.y;
  for (int off = 1; off < 64; off <<= 1) { s += __shfl_xor(s, off); sq += __shfl_xor(sq, off); }
  __shared__ float red[8];
  const int wv = tid >> 6;
  if ((tid & 63) == 0) { red[wv] = s; red[wv + 4] = sq; }
  __syncthreads();
  s = red[0] + red[1] + red[2] + red[3];
  sq = red[4] + red[5] + red[6] + red[7];
  const float mu = s * (1.0f / 512.0f);
  const float var = sq * (1.0f / 512.0f) - mu * mu;
  const float inv = rsqrtf(var + 1e-5f);
  const float2 wv2 = *reinterpret_cast<const float2*>(w + tid * 2);
  const float2 bv2 = *reinterpret_cast<const float2*>(b + tid * 2);
  const float h0 = (v.x - mu) * inv * wv2.x + bv2.x;
  const float h1 = (v.y - mu) * inv * wv2.y + bv2.y;
  unsigned u = (unsigned)(unsigned short)f2b(h0) | ((unsigned)(unsigned short)f2b(h1) << 16);
  *reinterpret_cast<unsigned*>(h + (size_t)row * 512 + tid * 2) = u;
}

// 128x128 tile GEMM via global_load_lds, both-sides-swizzled LDS [128][64].
// A[M][512] bf16 row-major, Bt[N][512] bf16 (B transposed).
// EPI=0: bias + fused RoPE, scatter q/k [bh][t][64], v^T [bh][d][t]
// EPI=1: out[row][col] = acc + bias (f32)
template <int EPI>
__global__ __launch_bounds__(256) void gemm128_kernel(const short* __restrict__ A,
                                                      const short* __restrict__ Bt,
                                                      const float* __restrict__ bias,
                                                      const float2* __restrict__ tab,
                                                      void* __restrict__ o0,
                                                      void* __restrict__ o1,
                                                      void* __restrict__ o2) {
  __shared__ short As[128 * 64];
  __shared__ short Bs[128 * 64];
  const int tid = threadIdx.x;
  const int lane = tid & 63, wave = tid >> 6;
  const int lr = lane & 15, lg = lane >> 4;
  const int wm = wave >> 1, wn = wave & 1;
  const int m0 = blockIdx.x * 128, n0 = blockIdx.y * 128;

  const int swz_col = ((lane & 7) ^ ((lane >> 3) & 7)) * 8;
  const short* Ag = A + (size_t)(m0 + wave * 32 + (lane >> 3)) * 512 + swz_col;
  const short* Bg = Bt + (size_t)(n0 + wave * 32 + (lane >> 3)) * 512 + swz_col;
  short* AsW = &As[(wave * 32) * 64];
  short* BsW = &Bs[(wave * 32) * 64];

  f32x4 acc[4][4] = {};

  for (int k0 = 0; k0 < 512; k0 += 64) {
#pragma unroll
    for (int i = 0; i < 4; ++i) {
      gll16(Ag + (size_t)i * 8 * 512 + k0, AsW + i * 8 * 64);
      gll16(Bg + (size_t)i * 8 * 512 + k0, BsW + i * 8 * 64);
    }
    __syncthreads();
#pragma unroll
    for (int ks = 0; ks < 2; ++ks) {
      bf16x8 af[4], bfr[4];
#pragma unroll
      for (int m = 0; m < 4; ++m)
        af[m] = lds16(As, wm * 64 + m * 16 + lr, ks * 64 + lg * 16);
#pragma unroll
      for (int n = 0; n < 4; ++n)
        bfr[n] = lds16(Bs, wn * 64 + n * 16 + lr, ks * 64 + lg * 16);
#pragma unroll
      for (int m = 0; m < 4; ++m)
#pragma unroll
        for (int n = 0; n < 4; ++n)
          acc[m][n] = __builtin_amdgcn_mfma_f32_16x16x32_bf16(af[m], bfr[n], acc[m][n], 0, 0, 0);
    }
    __syncthreads();
  }

  if (EPI == 0) {
    const int base = n0 + wn * 64;             // wave-uniform head window
    const int which = base >> 9;               // 0=q 1=k 2=v
    const int hh = (base & 511) >> 6;
    short* qp = (short*)o0; short* kp = (short*)o1; short* vtp = (short*)o2;
    const float b0 = bias[base + lr], b1 = bias[base + 16 + lr];
    const float b2 = bias[base + 32 + lr], b3 = bias[base + 48 + lr];
    const float QS = 0.125f * 1.4426950408889634f;  // 1/sqrt(dk) * log2(e), q only
#pragma unroll
    for (int m = 0; m < 4; ++m) {
      const int rowb = m0 + wm * 64 + m * 16 + lg * 4;
#pragma unroll
      for (int j = 0; j < 4; ++j) {
        const int t = (rowb + j) & 2047;
        const int bh = ((rowb + j) >> 11) * 8 + hh;
        float v0 = acc[m][0][j] + b0;
        float v1 = acc[m][1][j] + b1;
        float v2 = acc[m][2][j] + b2;
        float v3 = acc[m][3][j] + b3;
        if (which < 2) {
          const float2 cs0 = tab[t * 32 + lr];
          const float2 cs1 = tab[t * 32 + 16 + lr];
          float r0 = v0 * cs0.x - v2 * cs0.y;
          float r2 = v2 * cs0.x + v0 * cs0.y;
          float r1 = v1 * cs1.x - v3 * cs1.y;
          float r3 = v3 * cs1.x + v1 * cs1.y;
          if (which == 0) { r0 *= QS; r1 *= QS; r2 *= QS; r3 *= QS; }
          short* dst = (which == 0 ? qp : kp) + ((size_t)bh * TT + t) * 64;
          dst[lr] = f2b(r0); dst[16 + lr] = f2b(r1);
          dst[32 + lr] = f2b(r2); dst[48 + lr] = f2b(r3);
        } else {
          short* vb = vtp + (size_t)bh * 64 * TT + t;
          vb[(size_t)lr * TT] = f2b(v0);
          vb[(size_t)(16 + lr) * TT] = f2b(v1);
          vb[(size_t)(32 + lr) * TT] = f2b(v2);
          vb[(size_t)(48 + lr) * TT] = f2b(v3);
        }
      }
    }
  } else {
#pragma unroll
    for (int m = 0; m < 4; ++m)
#pragma unroll
      for (int n = 0; n < 4; ++n)
#pragma unroll
        for (int j = 0; j < 4; ++j) {
          const int row = m0 + wm * 64 + m * 16 + lg * 4 + j;
          const int col = n0 + wn * 64 + n * 16 + lr;
          ((float*)o0)[(size_t)row * 512 + col] = acc[m][n][j] + bias[col];
        }
  }
}

// Flash attention, swapped-QK^T 32x32x16, exp2 softmax, gll-staged dbuf pipeline.
// 8 waves x 32 q-rows = 256 q-rows/block; K/V staging amortized over 8 waves.
// grid: 512 linear blocks (XCD-swizzled). [round-7 proven structure]
__global__ __launch_bounds__(512) void attn_kernel(const short* __restrict__ q,
                                                   const short* __restrict__ k,
                                                   const short* __restrict__ vt,
                                                   const unsigned char* __restrict__ mask,
                                                   short* __restrict__ o) {
  __shared__ short Ks[2][64 * 64];
  __shared__ short Vs[2][64 * 64];
  __shared__ float psc[8][32];
  const int tid = threadIdx.x;
  const int lane = tid & 63, wave = tid >> 6;  // wave 0..7
  const int l31 = lane & 31, g = lane >> 5;
  const bool hi = (g != 0);
  // bijective XCD swizzle: 512 blocks, 8 XCDs -> 8 q-tiles of one bh per XCD
  const int nb = (blockIdx.x & 7) * 64 + (blockIdx.x >> 3);
  const int bh = nb >> 3, qt = nb & 7;
  const int bb = bh >> 3, hh = bh & 7;
  const int q0 = qt * 256 + wave * 32;
  const size_t bhT = (size_t)bh * TT;
  const unsigned char* maskb = mask + (size_t)bb * TT;

  // whole-row mask flag (hoisted): 2048 bytes = 512 dwords per batch row
  unsigned mor = 0;
  const unsigned* mw = (const unsigned*)maskb;
#pragma unroll
  for (int i = 0; i < 8; ++i) mor |= mw[lane + 64 * i];
  const bool masked = __any((int)(mor != 0));

  // Q as B-operand frags
  bf16x8 qf[4];
#pragma unroll
  for (int ds = 0; ds < 4; ++ds)
    qf[ds] = *reinterpret_cast<const bf16x8*>(q + (bhT + q0 + l31) * 64 + ds * 16 + g * 8);

  f32x16 oa0 = {}, oa1 = {};
  float m_run = 0.0f, l_run = 0.0f;

  // gll staging: wave w stages K rows [w*8, +8) and V d-rows [w*8, +8)
  const int swz_col = ((lane & 7) ^ ((lane >> 3) & 7)) * 8;
  const int r0 = wave * 8;
  const short* kg0 = k + (bhT + r0 + (lane >> 3)) * 64 + swz_col;
  const short* vg0 = vt + ((size_t)bh * 64 + r0 + (lane >> 3)) * TT + swz_col;

  // prologue: stage tile 0 into buffer 0
  gll16(kg0, &Ks[0][r0 * 64]);
  gll16(vg0, &Vs[0][r0 * 64]);
  __syncthreads();

  for (int kt = 0; kt < TT / 64; ++kt) {
    const int cur = kt & 1;
    if (kt < TT / 64 - 1) {  // async prefetch next tile into other buffer
      const int nxt = cur ^ 1;
      gll16(kg0 + (size_t)(kt + 1) * 64 * 64, &Ks[nxt][r0 * 64]);
      gll16(vg0 + (size_t)(kt + 1) * 64, &Vs[nxt][r0 * 64]);
    }

    const short* Kc = Ks[cur];
    const short* Vc = Vs[cur];

    // S^T = K Q^T
    f32x16 s0 = {}, s1 = {};
    __builtin_amdgcn_s_setprio(1);
#pragma unroll
    for (int ds = 0; ds < 4; ++ds) {
      const int cb = ds * 32 + g * 16;
      const bf16x8 ka0 = lds16(Kc, l31, cb);
      const bf16x8 ka1 = lds16(Kc, 32 + l31, cb);
      s0 = __builtin_amdgcn_mfma_f32_32x32x16_bf16(ka0, qf[ds], s0, 0, 0, 0);
      s1 = __builtin_amdgcn_mfma_f32_32x32x16_bf16(ka1, qf[ds], s1, 0, 0, 0);
    }
    __builtin_amdgcn_s_setprio(0);

    if (masked) {  // slow path: apply mask elementwise
#pragma unroll
      for (int r = 0; r < 16; ++r) {
        const int kk = (r & 3) + 8 * (r >> 2) + 4 * g;
        if (maskb[kt * 64 + kk]) s0[r] += -1e30f;
        if (maskb[kt * 64 + 32 + kk]) s1[r] += -1e30f;
      }
    }

    // row max over 64 keys: max3 tree + cross-half
    float b8[8];
#pragma unroll
    for (int i = 0; i < 8; ++i) b8[i] = max3f(s0[i], s0[i + 8], s1[i]);
    float c4[4];
#pragma unroll
    for (int i = 0; i < 4; ++i) c4[i] = fmaxf(s1[8 + i], s1[12 + i]);
    const float d0 = max3f(b8[0], b8[1], b8[2]);
    const float d1 = max3f(b8[3], b8[4], b8[5]);
    const float d2 = max3f(b8[6], b8[7], c4[0]);
    const float d3 = max3f(c4[1], c4[2], c4[3]);
    const float mx = fmaxf(max3f(d0, d1, d2), d3);
    const float pmax = fmaxf(mx, __shfl_xor(mx, 32));

    if (kt == 0) {
      m_run = pmax;
    } else if (!__all((int)(pmax - m_run <= 8.0f))) {
      const float nm = fmaxf(m_run, pmax);
      const float sc = ex2(m_run - nm);
      m_run = nm;
      l_run *= sc;
      if (lane < 32) psc[wave][l31] = sc;
      asm volatile("s_waitcnt lgkmcnt(0)" ::: "memory");
#pragma unroll
      for (int r = 0; r < 16; ++r) {
        const float s = psc[wave][(r & 3) + 8 * (r >> 2) + 4 * g];
        oa0[r] *= s; oa1[r] *= s;
      }
    }

    // P = exp2(S - m) in place
#pragma unroll
    for (int i = 0; i < 16; ++i) { s0[i] = ex2(s0[i] - m_run); s1[i] = ex2(s1[i] - m_run); }

    // row sum (pairwise tree)
    float a8[8];
#pragma unroll
    for (int i = 0; i < 8; ++i) a8[i] = (s0[i] + s0[i + 8]) + (s1[i] + s1[i + 8]);
    const float e0 = (a8[0] + a8[1]) + (a8[2] + a8[3]);
    const float e1 = (a8[4] + a8[5]) + (a8[6] + a8[7]);
    const float rsum = e0 + e1;
    l_run += rsum + __shfl_xor(rsum, 32);

    // P -> bf16 A-frags in-register
    bf16x8 pa[4];
    p_to_frags(s0, hi, &pa[0], &pa[1]);
    p_to_frags(s1, hi, &pa[2], &pa[3]);

    // O += P V
    __builtin_amdgcn_s_setprio(1);
#pragma unroll
    for (int ks = 0; ks < 4; ++ks) {
      const int cb = ks * 32 + g * 16;
      const bf16x8 vb0 = lds16(Vc, l31, cb);
      const bf16x8 vb1 = lds16(Vc, 32 + l31, cb);
      oa0 = __builtin_amdgcn_mfma_f32_32x32x16_bf16(pa[ks], vb0, oa0, 0, 0, 0);
      oa1 = __builtin_amdgcn_mfma_f32_32x32x16_bf16(pa[ks], vb1, oa1, 0, 0, 0);
    }
    __builtin_amdgcn_s_setprio(0);

    __syncthreads();  // drains vmcnt (prefetch) + lgkm; next buffer ready
  }

  // epilogue: O[q][d] / l
  const float linv = 1.0f / l_run;  // valid for q = l31
#pragma unroll
  for (int r = 0; r < 16; ++r) {
    const int qr = (r & 3) + 8 * (r >> 2) + 4 * g;
    const float lv = __shfl(linv, (lane & 32) | qr, 64);
    const int trow = q0 + qr;
    const size_t orow = ((size_t)bb * TT + trow) * 512 + hh * 64 + l31;
    o[orow]      = f2b(oa0[r] * lv);
    o[orow + 32] = f2b(oa1[r] * lv);
  }
}

extern "C" void kernel_launch(void* const* d_in, const int* in_sizes, int n_in,
                              void* d_out, int out_size, void* d_ws, size_t ws_size,
                              hipStream_t stream) {
  (void)in_sizes; (void)n_in; (void)out_size; (void)ws_size;
  const float* x = (const float*)d_in[0];
  const unsigned char* mask = (const unsigned char*)d_in[1];
  const float* ln_w = (const float*)d_in[2];
  const float* ln_b = (const float*)d_in[3];
  const float* w_qkv = (const float*)d_in[4];
  const float* b_qkv = (const float*)d_in[5];
  const float* w_o = (const float*)d_in[6];
  const float* b_o = (const float*)d_in[7];
  float* out = (float*)d_out;

  char* ws = (char*)d_ws;
  short* h_buf = (short*)(ws);                 // 16384*512 bf16 = 16 MB; reused as attn_out
  short* wqkvT = (short*)(ws + 16777216);      // 1536*512 bf16
  short* woT   = (short*)(ws + 18350080);      // 512*512 bf16
  short* q_ws  = (short*)(ws + 18874368);      // [64][2048][64] bf16
  short* k_ws  = (short*)(ws + 35651584);      // [64][2048][64] bf16
  short* vt_ws = (short*)(ws + 52428800);      // [64][64][2048] bf16
  float2* tab  = (float2*)(ws + 69206016);     // [2048][32] float2 = 512 KB

  hipLaunchKernelGGL(prep_kernel, dim3(512), dim3(256), 0, stream,
                     w_qkv, wqkvT, w_o, woT, tab);
  hipLaunchKernelGGL(ln_kernel, dim3(16384), dim3(256), 0, stream, x, ln_w, ln_b, h_buf);
  hipLaunchKernelGGL((gemm128_kernel<0>), dim3(128, 12), dim3(256), 0, stream,
                     h_buf, wqkvT, b_qkv, tab, (void*)q_ws, (void*)k_ws, (void*)vt_ws);
  hipLaunchKernelGGL(attn_kernel, dim3(512), dim3(512), 0, stream,
                     q_ws, k_ws, vt_ws, mask, h_buf);
  hipLaunchKernelGGL((gemm128_kernel<1>), dim3(128, 4), dim3(256), 0, stream,
                     h_buf, woT, b_o, tab, (void*)out, nullptr, nullptr);
}

// Round 11
// 167.547 us; speedup vs baseline: 1.8849x; 1.0459x over previous
//
#include <hip/hip_runtime.h>
#include <hip/hip_bf16.h>

#define TT 2048

typedef __attribute__((ext_vector_type(8))) short bf16x8;
typedef __attribute__((ext_vector_type(4))) float f32x4;
typedef __attribute__((ext_vector_type(16))) float f32x16;
typedef __attribute__((ext_vector_type(2))) int i32x2;

__device__ __forceinline__ short f2b(float f) {
  union { float f; unsigned u; } a; a.f = f;
  unsigned r = a.u + 0x7fffu + ((a.u >> 16) & 1u);
  return (short)(r >> 16);
}
__device__ __forceinline__ unsigned cvtpk(float lo, float hi) {
  unsigned r;
  asm("v_cvt_pk_bf16_f32 %0, %1, %2" : "=v"(r) : "v"(lo), "v"(hi));
  return r;
}
__device__ __forceinline__ float max3f(float a, float b, float c) {
  float d;
  asm("v_max3_f32 %0, %1, %2, %3" : "=v"(d) : "v"(a), "v"(b), "v"(c));
  return d;
}
__device__ __forceinline__ float ex2(float x) {
#if __has_builtin(__builtin_amdgcn_exp2f)
  return __builtin_amdgcn_exp2f(x);
#else
  return exp2f(x);
#endif
}
// async global->LDS, 16B per lane; lds dest = wave-uniform base + lane*16
__device__ __forceinline__ void gll16(const void* g, void* l) {
  __builtin_amdgcn_global_load_lds(
      (const __attribute__((address_space(1))) unsigned int*)g,
      (__attribute__((address_space(3))) unsigned int*)l, 16, 0, 0);
}
// exchange high-32 lanes of a with low-32 lanes of b
__device__ __forceinline__ void swap_halves(unsigned &a, unsigned &b, bool hi) {
#if __has_builtin(__builtin_amdgcn_permlane32_swap)
  i32x2 r = __builtin_amdgcn_permlane32_swap((int)a, (int)b, false, false);
  a = (unsigned)r[0]; b = (unsigned)r[1];
#else
  unsigned as = (unsigned)__shfl_xor((int)a, 32);
  unsigned bs = (unsigned)__shfl_xor((int)b, 32);
  unsigned na = hi ? bs : a;
  unsigned nb = hi ? b : as;
  a = na; b = nb;
#endif
}

// 16 f32 P-values (one 32-row S^T fragment) -> two PV A-frags
__device__ __forceinline__ void p_to_frags(const f32x16 p, bool hi, bf16x8* f0, bf16x8* f1) {
  unsigned A[4][2];
#pragma unroll
  for (int u = 0; u < 4; ++u)
#pragma unroll
    for (int c = 0; c < 2; ++c)
      A[u][c] = cvtpk(p[4 * u + 2 * c], p[4 * u + 2 * c + 1]);
  swap_halves(A[0][0], A[1][0], hi);
  swap_halves(A[0][1], A[1][1], hi);
  swap_halves(A[2][0], A[3][0], hi);
  swap_halves(A[2][1], A[3][1], hi);
  union { unsigned u[4]; bf16x8 v; } r0, r1;
  r0.u[0] = A[0][0]; r0.u[1] = A[0][1]; r0.u[2] = A[1][0]; r0.u[3] = A[1][1];
  r1.u[0] = A[2][0]; r1.u[1] = A[2][1]; r1.u[2] = A[3][0]; r1.u[3] = A[3][1];
  *f0 = r0.v; *f1 = r1.v;
}

// swizzled LDS access, 128B rows: byte col ^ ((row&7)<<4)
__device__ __forceinline__ bf16x8 lds16(const short* base, int row, int cb) {
  return *reinterpret_cast<const bf16x8*>(
      reinterpret_cast<const char*>(base) + row * 128 + (cb ^ ((row & 7) << 4)));
}

// fused prep: transpose-cast w_qkv (192 blocks) + w_o (64 blocks) + RoPE table (256)
__global__ __launch_bounds__(256) void prep_kernel(const float* __restrict__ w_qkv,
                                                   short* __restrict__ wqkvT,
                                                   const float* __restrict__ w_o,
                                                   short* __restrict__ woT,
                                                   float2* __restrict__ tab) {
  __shared__ float t[64][65];
  const int id = blockIdx.x;
  if (id < 256) {
    const float* src; short* dst; int N, n0, k0;
    if (id < 192) { src = w_qkv; dst = wqkvT; N = 1536; n0 = (id % 24) * 64; k0 = (id / 24) * 64; }
    else { const int i2 = id - 192; src = w_o; dst = woT; N = 512; n0 = (i2 & 7) * 64; k0 = (i2 >> 3) * 64; }
    const int c = threadIdx.x & 63, r4 = threadIdx.x >> 6;
#pragma unroll
    for (int i = 0; i < 16; ++i) {
      const int r = i * 4 + r4;
      t[r][c] = src[(size_t)(k0 + r) * N + n0 + c];
    }
    __syncthreads();
#pragma unroll
    for (int i = 0; i < 16; ++i) {
      const int r = i * 4 + r4;
      dst[(size_t)(n0 + r) * 512 + k0 + c] = f2b(t[c][r]);
    }
  } else {
    const int idx = (id - 256) * 256 + threadIdx.x;  // 65536
    const int i = idx & 31, tt = idx >> 5;
    const float inv_freq = __expf(-(float)i * (9.210340371976184f / 32.0f));
    float sv, cv;
    sincosf((float)tt * inv_freq, &sv, &cv);
    tab[idx] = make_float2(cv, sv);
  }
}

// LayerNorm rows of 512, fp32 in, bf16 out; 2 rows/block, float4 loads
__global__ __launch_bounds__(256) void ln_kernel(const float* __restrict__ x,
                                                 const float* __restrict__ w,
                                                 const float* __restrict__ b,
                                                 short* __restrict__ h) {
  const int tid = threadIdx.x;
  const int row = blockIdx.x * 2 + (tid >> 7);   // 128 threads per row
  const int c = tid & 127;                        // 4 f32 each
  const float4 v = *reinterpret_cast<const float4*>(x + (size_t)row * 512 + c * 4);
  float s = (v.x + v.y) + (v.z + v.w);
  float sq = (v.x * v.x + v.y * v.y) + (v.z * v.z + v.w * v.w);
  for (int off = 1; off < 64; off <<= 1) { s += __shfl_xor(s, off); sq += __shfl_xor(sq, off); }
  __shared__ float red[8];
  const int wv = tid >> 6;  // 0..3 (two per row)
  if ((tid & 63) == 0) { red[wv] = s; red[wv + 4] = sq; }
  __syncthreads();
  const int rb = (tid >> 7) ? 2 : 0;
  s = red[rb] + red[rb + 1];
  sq = red[rb + 4] + red[rb + 5];
  const float mu = s * (1.0f / 512.0f);
  const float var = sq * (1.0f / 512.0f) - mu * mu;
  const float inv = rsqrtf(var + 1e-5f);
  const float4 wv4 = *reinterpret_cast<const float4*>(w + c * 4);
  const float4 bv4 = *reinterpret_cast<const float4*>(b + c * 4);
  const float h0 = (v.x - mu) * inv * wv4.x + bv4.x;
  const float h1 = (v.y - mu) * inv * wv4.y + bv4.y;
  const float h2 = (v.z - mu) * inv * wv4.z + bv4.z;
  const float h3 = (v.w - mu) * inv * wv4.w + bv4.w;
  uint2 u;
  u.x = (unsigned)(unsigned short)f2b(h0) | ((unsigned)(unsigned short)f2b(h1) << 16);
  u.y = (unsigned)(unsigned short)f2b(h2) | ((unsigned)(unsigned short)f2b(h3) << 16);
  *reinterpret_cast<uint2*>(h + (size_t)row * 512 + c * 4) = u;
}

// 128x128 tile GEMM via global_load_lds, both-sides-swizzled LDS [128][64].
// A[M][512] bf16 row-major, Bt[N][512] bf16 (B transposed).
// EPI=0: bias + fused RoPE, scatter q/k [bh][t][64], v^T [bh][d][t]
// EPI=1: out[row][col] = acc + bias (f32)
template <int EPI>
__global__ __launch_bounds__(256) void gemm128_kernel(const short* __restrict__ A,
                                                      const short* __restrict__ Bt,
                                                      const float* __restrict__ bias,
                                                      const float2* __restrict__ tab,
                                                      void* __restrict__ o0,
                                                      void* __restrict__ o1,
                                                      void* __restrict__ o2) {
  __shared__ short As[128 * 64];
  __shared__ short Bs[128 * 64];
  const int tid = threadIdx.x;
  const int lane = tid & 63, wave = tid >> 6;
  const int lr = lane & 15, lg = lane >> 4;
  const int wm = wave >> 1, wn = wave & 1;
  const int m0 = blockIdx.x * 128, n0 = blockIdx.y * 128;

  const int swz_col = ((lane & 7) ^ ((lane >> 3) & 7)) * 8;
  const short* Ag = A + (size_t)(m0 + wave * 32 + (lane >> 3)) * 512 + swz_col;
  const short* Bg = Bt + (size_t)(n0 + wave * 32 + (lane >> 3)) * 512 + swz_col;
  short* AsW = &As[(wave * 32) * 64];
  short* BsW = &Bs[(wave * 32) * 64];

  f32x4 acc[4][4] = {};

  for (int k0 = 0; k0 < 512; k0 += 64) {
#pragma unroll
    for (int i = 0; i < 4; ++i) {
      gll16(Ag + (size_t)i * 8 * 512 + k0, AsW + i * 8 * 64);
      gll16(Bg + (size_t)i * 8 * 512 + k0, BsW + i * 8 * 64);
    }
    __syncthreads();
#pragma unroll
    for (int ks = 0; ks < 2; ++ks) {
      bf16x8 af[4], bfr[4];
#pragma unroll
      for (int m = 0; m < 4; ++m)
        af[m] = lds16(As, wm * 64 + m * 16 + lr, ks * 64 + lg * 16);
#pragma unroll
      for (int n = 0; n < 4; ++n)
        bfr[n] = lds16(Bs, wn * 64 + n * 16 + lr, ks * 64 + lg * 16);
#pragma unroll
      for (int m = 0; m < 4; ++m)
#pragma unroll
        for (int n = 0; n < 4; ++n)
          acc[m][n] = __builtin_amdgcn_mfma_f32_16x16x32_bf16(af[m], bfr[n], acc[m][n], 0, 0, 0);
    }
    __syncthreads();
  }

  if (EPI == 0) {
    const int base = n0 + wn * 64;             // wave-uniform head window
    const int which = base >> 9;               // 0=q 1=k 2=v
    const int hh = (base & 511) >> 6;
    short* qp = (short*)o0; short* kp = (short*)o1; short* vtp = (short*)o2;
    const float b0 = bias[base + lr], b1 = bias[base + 16 + lr];
    const float b2 = bias[base + 32 + lr], b3 = bias[base + 48 + lr];
    const float QS = 0.125f * 1.4426950408889634f;  // 1/sqrt(dk) * log2(e), q only
#pragma unroll
    for (int m = 0; m < 4; ++m) {
      const int rowb = m0 + wm * 64 + m * 16 + lg * 4;
#pragma unroll
      for (int j = 0; j < 4; ++j) {
        const int t = (rowb + j) & 2047;
        const int bh = ((rowb + j) >> 11) * 8 + hh;
        float v0 = acc[m][0][j] + b0;
        float v1 = acc[m][1][j] + b1;
        float v2 = acc[m][2][j] + b2;
        float v3 = acc[m][3][j] + b3;
        if (which < 2) {
          const float2 cs0 = tab[t * 32 + lr];
          const float2 cs1 = tab[t * 32 + 16 + lr];
          float r0 = v0 * cs0.x - v2 * cs0.y;
          float r2 = v2 * cs0.x + v0 * cs0.y;
          float r1 = v1 * cs1.x - v3 * cs1.y;
          float r3 = v3 * cs1.x + v1 * cs1.y;
          if (which == 0) { r0 *= QS; r1 *= QS; r2 *= QS; r3 *= QS; }
          short* dst = (which == 0 ? qp : kp) + ((size_t)bh * TT + t) * 64;
          dst[lr] = f2b(r0); dst[16 + lr] = f2b(r1);
          dst[32 + lr] = f2b(r2); dst[48 + lr] = f2b(r3);
        } else {
          short* vb = vtp + (size_t)bh * 64 * TT + t;
          vb[(size_t)lr * TT] = f2b(v0);
          vb[(size_t)(16 + lr) * TT] = f2b(v1);
          vb[(size_t)(32 + lr) * TT] = f2b(v2);
          vb[(size_t)(48 + lr) * TT] = f2b(v3);
        }
      }
    }
  } else {
#pragma unroll
    for (int m = 0; m < 4; ++m)
#pragma unroll
      for (int n = 0; n < 4; ++n)
#pragma unroll
        for (int j = 0; j < 4; ++j) {
          const int row = m0 + wm * 64 + m * 16 + lg * 4 + j;
          const int col = n0 + wn * 64 + n * 16 + lr;
          ((float*)o0)[(size_t)row * 512 + col] = acc[m][n][j] + bias[col];
        }
  }
}

// Flash attention, swapped-QK^T 32x32x16, exp2 softmax, gll-staged pipeline.
// 8 waves x 32 q-rows = 256 q-rows/block. Depth-2: 2 K-tiles per barrier,
// 4-deep K/V LDS rings (write slots (kt+2)&3,(kt+3)&3 disjoint from read
// slots kt&3,(kt+1)&3; barrier-per-2-tiles keeps ring safe).
// grid: 512 linear blocks (XCD-swizzled).
__global__ __launch_bounds__(512) void attn_kernel(const short* __restrict__ q,
                                                   const short* __restrict__ k,
                                                   const short* __restrict__ vt,
                                                   const unsigned char* __restrict__ mask,
                                                   short* __restrict__ o) {
  __shared__ short Ks[4][64 * 64];
  __shared__ short Vs[4][64 * 64];
  __shared__ float psc[8][32];
  const int tid = threadIdx.x;
  const int lane = tid & 63, wave = tid >> 6;  // wave 0..7
  const int l31 = lane & 31, g = lane >> 5;
  const bool hi = (g != 0);
  // bijective XCD swizzle: 512 blocks, 8 XCDs -> 8 q-tiles of one bh per XCD
  const int nb = (blockIdx.x & 7) * 64 + (blockIdx.x >> 3);
  const int bh = nb >> 3, qt = nb & 7;
  const int bb = bh >> 3, hh = bh & 7;
  const int q0 = qt * 256 + wave * 32;
  const size_t bhT = (size_t)bh * TT;
  const unsigned char* maskb = mask + (size_t)bb * TT;

  // whole-row mask flag (hoisted)
  unsigned mor = 0;
  const unsigned* mw = (const unsigned*)maskb;
#pragma unroll
  for (int i = 0; i < 8; ++i) mor |= mw[lane + 64 * i];
  const bool masked = __any((int)(mor != 0));

  // Q as B-operand frags
  bf16x8 qf[4];
#pragma unroll
  for (int ds = 0; ds < 4; ++ds)
    qf[ds] = *reinterpret_cast<const bf16x8*>(q + (bhT + q0 + l31) * 64 + ds * 16 + g * 8);

  f32x16 oa0 = {}, oa1 = {};
  float m_run = 0.0f, l_run = 0.0f;

  // gll staging: wave w stages K rows [w*8, +8) and V d-rows [w*8, +8)
  const int swz_col = ((lane & 7) ^ ((lane >> 3) & 7)) * 8;
  const int r0 = wave * 8;
  const short* kg0 = k + (bhT + r0 + (lane >> 3)) * 64 + swz_col;
  const short* vg0 = vt + ((size_t)bh * 64 + r0 + (lane >> 3)) * TT + swz_col;

  auto stage = [&](int kt, int buf) {
    gll16(kg0 + (size_t)kt * 4096, &Ks[buf][r0 * 64]);
    gll16(vg0 + (size_t)kt * 64,   &Vs[buf][r0 * 64]);
  };

  auto tile = [&](int kt, const short* Kc, const short* Vc) {
    // S^T = K Q^T
    f32x16 s0 = {}, s1 = {};
    __builtin_amdgcn_s_setprio(1);
#pragma unroll
    for (int ds = 0; ds < 4; ++ds) {
      const int cb = ds * 32 + g * 16;
      const bf16x8 ka0 = lds16(Kc, l31, cb);
      const bf16x8 ka1 = lds16(Kc, 32 + l31, cb);
      s0 = __builtin_amdgcn_mfma_f32_32x32x16_bf16(ka0, qf[ds], s0, 0, 0, 0);
      s1 = __builtin_amdgcn_mfma_f32_32x32x16_bf16(ka1, qf[ds], s1, 0, 0, 0);
    }
    __builtin_amdgcn_s_setprio(0);

    if (masked) {
#pragma unroll
      for (int r = 0; r < 16; ++r) {
        const int kk = (r & 3) + 8 * (r >> 2) + 4 * g;
        if (maskb[kt * 64 + kk]) s0[r] += -1e30f;
        if (maskb[kt * 64 + 32 + kk]) s1[r] += -1e30f;
      }
    }

    // row max over 64 keys: max3 tree + cross-half
    float b8[8];
#pragma unroll
    for (int i = 0; i < 8; ++i) b8[i] = max3f(s0[i], s0[i + 8], s1[i]);
    float c4[4];
#pragma unroll
    for (int i = 0; i < 4; ++i) c4[i] = fmaxf(s1[8 + i], s1[12 + i]);
    const float d0 = max3f(b8[0], b8[1], b8[2]);
    const float d1 = max3f(b8[3], b8[4], b8[5]);
    const float d2 = max3f(b8[6], b8[7], c4[0]);
    const float d3 = max3f(c4[1], c4[2], c4[3]);
    const float mx = fmaxf(max3f(d0, d1, d2), d3);
    const float pmax = fmaxf(mx, __shfl_xor(mx, 32));

    if (kt == 0) {
      m_run = pmax;
    } else if (!__all((int)(pmax - m_run <= 8.0f))) {
      const float nm = fmaxf(m_run, pmax);
      const float sc = ex2(m_run - nm);
      m_run = nm;
      l_run *= sc;
      if (lane < 32) psc[wave][l31] = sc;
      asm volatile("s_waitcnt lgkmcnt(0)" ::: "memory");
#pragma unroll
      for (int r = 0; r < 16; ++r) {
        const float s = psc[wave][(r & 3) + 8 * (r >> 2) + 4 * g];
        oa0[r] *= s; oa1[r] *= s;
      }
    }

    // P = exp2(S - m) in place
#pragma unroll
    for (int i = 0; i < 16; ++i) { s0[i] = ex2(s0[i] - m_run); s1[i] = ex2(s1[i] - m_run); }

    // row sum (pairwise tree)
    float a8[8];
#pragma unroll
    for (int i = 0; i < 8; ++i) a8[i] = (s0[i] + s0[i + 8]) + (s1[i] + s1[i + 8]);
    const float e0 = (a8[0] + a8[1]) + (a8[2] + a8[3]);
    const float e1 = (a8[4] + a8[5]) + (a8[6] + a8[7]);
    const float rsum = e0 + e1;
    l_run += rsum + __shfl_xor(rsum, 32);

    // P -> bf16 A-frags in-register
    bf16x8 pa[4];
    p_to_frags(s0, hi, &pa[0], &pa[1]);
    p_to_frags(s1, hi, &pa[2], &pa[3]);

    // O += P V
    __builtin_amdgcn_s_setprio(1);
#pragma unroll
    for (int ks = 0; ks < 4; ++ks) {
      const int cb = ks * 32 + g * 16;
      const bf16x8 vb0 = lds16(Vc, l31, cb);
      const bf16x8 vb1 = lds16(Vc, 32 + l31, cb);
      oa0 = __builtin_amdgcn_mfma_f32_32x32x16_bf16(pa[ks], vb0, oa0, 0, 0, 0);
      oa1 = __builtin_amdgcn_mfma_f32_32x32x16_bf16(pa[ks], vb1, oa1, 0, 0, 0);
    }
    __builtin_amdgcn_s_setprio(0);
  };

  // prologue: stage tiles 0 and 1
  stage(0, 0);
  stage(1, 1);
  __syncthreads();

  for (int kt = 0; kt < TT / 64; kt += 2) {
    if (kt + 2 < TT / 64) stage(kt + 2, (kt + 2) & 3);
    if (kt + 3 < TT / 64) stage(kt + 3, (kt + 3) & 3);
    tile(kt,     Ks[kt & 3],       Vs[kt & 3]);
    tile(kt + 1, Ks[(kt + 1) & 3], Vs[(kt + 1) & 3]);
    __syncthreads();  // drains prefetch vmcnt; frees read slots for next ring pass
  }

  // epilogue: O[q][d] / l
  const float linv = 1.0f / l_run;  // valid for q = l31
#pragma unroll
  for (int r = 0; r < 16; ++r) {
    const int qr = (r & 3) + 8 * (r >> 2) + 4 * g;
    const float lv = __shfl(linv, (lane & 32) | qr, 64);
    const int trow = q0 + qr;
    const size_t orow = ((size_t)bb * TT + trow) * 512 + hh * 64 + l31;
    o[orow]      = f2b(oa0[r] * lv);
    o[orow + 32] = f2b(oa1[r] * lv);
  }
}

extern "C" void kernel_launch(void* const* d_in, const int* in_sizes, int n_in,
                              void* d_out, int out_size, void* d_ws, size_t ws_size,
                              hipStream_t stream) {
  (void)in_sizes; (void)n_in; (void)out_size; (void)ws_size;
  const float* x = (const float*)d_in[0];
  const unsigned char* mask = (const unsigned char*)d_in[1];
  const float* ln_w = (const float*)d_in[2];
  const float* ln_b = (const float*)d_in[3];
  const float* w_qkv = (const float*)d_in[4];
  const float* b_qkv = (const float*)d_in[5];
  const float* w_o = (const float*)d_in[6];
  const float* b_o = (const float*)d_in[7];
  float* out = (float*)d_out;

  char* ws = (char*)d_ws;
  short* h_buf = (short*)(ws);                 // 16384*512 bf16 = 16 MB; reused as attn_out
  short* wqkvT = (short*)(ws + 16777216);      // 1536*512 bf16
  short* woT   = (short*)(ws + 18350080);      // 512*512 bf16
  short* q_ws  = (short*)(ws + 18874368);      // [64][2048][64] bf16
  short* k_ws  = (short*)(ws + 35651584);      // [64][2048][64] bf16
  short* vt_ws = (short*)(ws + 52428800);      // [64][64][2048] bf16
  float2* tab  = (float2*)(ws + 69206016);     // [2048][32] float2 = 512 KB

  hipLaunchKernelGGL(prep_kernel, dim3(512), dim3(256), 0, stream,
                     w_qkv, wqkvT, w_o, woT, tab);
  hipLaunchKernelGGL(ln_kernel, dim3(8192), dim3(256), 0, stream, x, ln_w, ln_b, h_buf);
  hipLaunchKernelGGL((gemm128_kernel<0>), dim3(128, 12), dim3(256), 0, stream,
                     h_buf, wqkvT, b_qkv, tab, (void*)q_ws, (void*)k_ws, (void*)vt_ws);
  hipLaunchKernelGGL(attn_kernel, dim3(512), dim3(512), 0, stream,
                     q_ws, k_ws, vt_ws, mask, h_buf);
  hipLaunchKernelGGL((gemm128_kernel<1>), dim3(128, 4), dim3(256), 0, stream,
                     h_buf, woT, b_o, tab, (void*)out, nullptr, nullptr);
}

// Round 12
// 164.490 us; speedup vs baseline: 1.9199x; 1.0186x over previous
//
#include <hip/hip_runtime.h>
#include <hip/hip_bf16.h>

#define TT 2048

typedef __attribute__((ext_vector_type(8))) short bf16x8;
typedef __attribute__((ext_vector_type(4))) float f32x4;
typedef __attribute__((ext_vector_type(16))) float f32x16;
typedef __attribute__((ext_vector_type(2))) int i32x2;

__device__ __forceinline__ short f2b(float f) {
  union { float f; unsigned u; } a; a.f = f;
  unsigned r = a.u + 0x7fffu + ((a.u >> 16) & 1u);
  return (short)(r >> 16);
}
__device__ __forceinline__ unsigned cvtpk(float lo, float hi) {
  unsigned r;
  asm("v_cvt_pk_bf16_f32 %0, %1, %2" : "=v"(r) : "v"(lo), "v"(hi));
  return r;
}
__device__ __forceinline__ float max3f(float a, float b, float c) {
  float d;
  asm("v_max3_f32 %0, %1, %2, %3" : "=v"(d) : "v"(a), "v"(b), "v"(c));
  return d;
}
__device__ __forceinline__ float ex2(float x) {
#if __has_builtin(__builtin_amdgcn_exp2f)
  return __builtin_amdgcn_exp2f(x);
#else
  return exp2f(x);
#endif
}
// async global->LDS, 16B per lane; lds dest = wave-uniform base + lane*16
__device__ __forceinline__ void gll16(const void* g, void* l) {
  __builtin_amdgcn_global_load_lds(
      (const __attribute__((address_space(1))) unsigned int*)g,
      (__attribute__((address_space(3))) unsigned int*)l, 16, 0, 0);
}
// exchange high-32 lanes of a with low-32 lanes of b
__device__ __forceinline__ void swap_halves(unsigned &a, unsigned &b, bool hi) {
#if __has_builtin(__builtin_amdgcn_permlane32_swap)
  i32x2 r = __builtin_amdgcn_permlane32_swap((int)a, (int)b, false, false);
  a = (unsigned)r[0]; b = (unsigned)r[1];
#else
  unsigned as = (unsigned)__shfl_xor((int)a, 32);
  unsigned bs = (unsigned)__shfl_xor((int)b, 32);
  unsigned na = hi ? bs : a;
  unsigned nb = hi ? b : as;
  a = na; b = nb;
#endif
}

// 16 f32 P-values (one 32-row S^T fragment) -> two PV A-frags
__device__ __forceinline__ void p_to_frags(const f32x16 p, bool hi, bf16x8* f0, bf16x8* f1) {
  unsigned A[4][2];
#pragma unroll
  for (int u = 0; u < 4; ++u)
#pragma unroll
    for (int c = 0; c < 2; ++c)
      A[u][c] = cvtpk(p[4 * u + 2 * c], p[4 * u + 2 * c + 1]);
  swap_halves(A[0][0], A[1][0], hi);
  swap_halves(A[0][1], A[1][1], hi);
  swap_halves(A[2][0], A[3][0], hi);
  swap_halves(A[2][1], A[3][1], hi);
  union { unsigned u[4]; bf16x8 v; } r0, r1;
  r0.u[0] = A[0][0]; r0.u[1] = A[0][1]; r0.u[2] = A[1][0]; r0.u[3] = A[1][1];
  r1.u[0] = A[2][0]; r1.u[1] = A[2][1]; r1.u[2] = A[3][0]; r1.u[3] = A[3][1];
  *f0 = r0.v; *f1 = r1.v;
}

// swizzled LDS access, 128B rows: byte col ^ ((row&7)<<4)
__device__ __forceinline__ bf16x8 lds16(const short* base, int row, int cb) {
  return *reinterpret_cast<const bf16x8*>(
      reinterpret_cast<const char*>(base) + row * 128 + (cb ^ ((row & 7) << 4)));
}

// fused: LayerNorm (blocks 0..8191) + weight transpose-cast (8192..8447) +
// RoPE table (8448..8703)
__global__ __launch_bounds__(256) void prepln_kernel(const float* __restrict__ x,
                                                     const float* __restrict__ lnw,
                                                     const float* __restrict__ lnb,
                                                     short* __restrict__ h,
                                                     const float* __restrict__ w_qkv,
                                                     short* __restrict__ wqkvT,
                                                     const float* __restrict__ w_o,
                                                     short* __restrict__ woT,
                                                     float2* __restrict__ tab) {
  __shared__ float t[64][65];
  const int id = blockIdx.x;
  const int tid = threadIdx.x;
  if (id < 8192) {
    // LayerNorm: 2 rows/block, float4 loads
    const int row = id * 2 + (tid >> 7);
    const int c = tid & 127;
    const float4 v = *reinterpret_cast<const float4*>(x + (size_t)row * 512 + c * 4);
    float s = (v.x + v.y) + (v.z + v.w);
    float sq = (v.x * v.x + v.y * v.y) + (v.z * v.z + v.w * v.w);
    for (int off = 1; off < 64; off <<= 1) { s += __shfl_xor(s, off); sq += __shfl_xor(sq, off); }
    __shared__ float red[8];
    const int wv = tid >> 6;
    if ((tid & 63) == 0) { red[wv] = s; red[wv + 4] = sq; }
    __syncthreads();
    const int rb = (tid >> 7) ? 2 : 0;
    s = red[rb] + red[rb + 1];
    sq = red[rb + 4] + red[rb + 5];
    const float mu = s * (1.0f / 512.0f);
    const float var = sq * (1.0f / 512.0f) - mu * mu;
    const float inv = rsqrtf(var + 1e-5f);
    const float4 wv4 = *reinterpret_cast<const float4*>(lnw + c * 4);
    const float4 bv4 = *reinterpret_cast<const float4*>(lnb + c * 4);
    const float h0 = (v.x - mu) * inv * wv4.x + bv4.x;
    const float h1 = (v.y - mu) * inv * wv4.y + bv4.y;
    const float h2 = (v.z - mu) * inv * wv4.z + bv4.z;
    const float h3 = (v.w - mu) * inv * wv4.w + bv4.w;
    uint2 u;
    u.x = (unsigned)(unsigned short)f2b(h0) | ((unsigned)(unsigned short)f2b(h1) << 16);
    u.y = (unsigned)(unsigned short)f2b(h2) | ((unsigned)(unsigned short)f2b(h3) << 16);
    *reinterpret_cast<uint2*>(h + (size_t)row * 512 + c * 4) = u;
  } else if (id < 8448) {
    const int id2 = id - 8192;
    const float* src; short* dst; int N, n0, k0;
    if (id2 < 192) { src = w_qkv; dst = wqkvT; N = 1536; n0 = (id2 % 24) * 64; k0 = (id2 / 24) * 64; }
    else { const int i2 = id2 - 192; src = w_o; dst = woT; N = 512; n0 = (i2 & 7) * 64; k0 = (i2 >> 3) * 64; }
    const int c = tid & 63, r4 = tid >> 6;
#pragma unroll
    for (int i = 0; i < 16; ++i) {
      const int r = i * 4 + r4;
      t[r][c] = src[(size_t)(k0 + r) * N + n0 + c];
    }
    __syncthreads();
#pragma unroll
    for (int i = 0; i < 16; ++i) {
      const int r = i * 4 + r4;
      dst[(size_t)(n0 + r) * 512 + k0 + c] = f2b(t[c][r]);
    }
  } else {
    const int idx = (id - 8448) * 256 + tid;  // 65536
    const int i = idx & 31, tt = idx >> 5;
    const float inv_freq = __expf(-(float)i * (9.210340371976184f / 32.0f));
    float sv, cv;
    sincosf((float)tt * inv_freq, &sv, &cv);
    tab[idx] = make_float2(cv, sv);
  }
}

// 128x128 tile GEMM via global_load_lds, both-sides-swizzled LDS [128][64],
// T4 pipeline: counted vmcnt + raw barriers (no vmcnt(0) drain in loop).
// A[M][512] bf16 row-major, Bt[N][512] bf16 (B transposed).
// EPI=0: bias + fused RoPE, scatter q/k [bh][t][64], v^T [bh][d][t]
// EPI=1: out[row][col] = acc + bias (f32)
template <int EPI>
__global__ __launch_bounds__(256) void gemm128_kernel(const short* __restrict__ A,
                                                      const short* __restrict__ Bt,
                                                      const float* __restrict__ bias,
                                                      const float2* __restrict__ tab,
                                                      void* __restrict__ o0,
                                                      void* __restrict__ o1,
                                                      void* __restrict__ o2) {
  __shared__ short As[2][128 * 64];
  __shared__ short Bs[2][128 * 64];
  const int tid = threadIdx.x;
  const int lane = tid & 63, wave = tid >> 6;
  const int lr = lane & 15, lg = lane >> 4;
  const int wm = wave >> 1, wn = wave & 1;
  const int m0 = blockIdx.x * 128, n0 = blockIdx.y * 128;

  const int swz_col = ((lane & 7) ^ ((lane >> 3) & 7)) * 8;
  const short* Ag = A + (size_t)(m0 + wave * 32 + (lane >> 3)) * 512 + swz_col;
  const short* Bg = Bt + (size_t)(n0 + wave * 32 + (lane >> 3)) * 512 + swz_col;

  f32x4 acc[4][4] = {};

  auto stage = [&](int kk, int buf) {
#pragma unroll
    for (int i = 0; i < 4; ++i) {
      gll16(Ag + (size_t)i * 8 * 512 + kk * 64, &As[buf][(wave * 32 + i * 8) * 64]);
      gll16(Bg + (size_t)i * 8 * 512 + kk * 64, &Bs[buf][(wave * 32 + i * 8) * 64]);
    }
  };
  auto compute = [&](int buf) {
#pragma unroll
    for (int ks = 0; ks < 2; ++ks) {
      bf16x8 af[4], bfr[4];
#pragma unroll
      for (int m = 0; m < 4; ++m)
        af[m] = lds16(As[buf], wm * 64 + m * 16 + lr, ks * 64 + lg * 16);
#pragma unroll
      for (int n = 0; n < 4; ++n)
        bfr[n] = lds16(Bs[buf], wn * 64 + n * 16 + lr, ks * 64 + lg * 16);
#pragma unroll
      for (int m = 0; m < 4; ++m)
#pragma unroll
        for (int n = 0; n < 4; ++n)
          acc[m][n] = __builtin_amdgcn_mfma_f32_16x16x32_bf16(af[m], bfr[n], acc[m][n], 0, 0, 0);
    }
  };

  stage(0, 0);
  for (int kk = 0; kk < 7; ++kk) {
    stage(kk + 1, (kk + 1) & 1);
    // wait only tile kk's 8 glls (kk+1's 8 stay in flight across the barrier)
    asm volatile("s_waitcnt vmcnt(8)" ::: "memory");
    __builtin_amdgcn_s_barrier();
    __builtin_amdgcn_sched_barrier(0);
    compute(kk & 1);
    __builtin_amdgcn_s_barrier();  // WAR: all waves done reading buf kk&1
  }
  asm volatile("s_waitcnt vmcnt(0)" ::: "memory");
  __builtin_amdgcn_s_barrier();
  __builtin_amdgcn_sched_barrier(0);
  compute(1);  // tile 7

  if (EPI == 0) {
    const int base = n0 + wn * 64;             // wave-uniform head window
    const int which = base >> 9;               // 0=q 1=k 2=v
    const int hh = (base & 511) >> 6;
    short* qp = (short*)o0; short* kp = (short*)o1; short* vtp = (short*)o2;
    const float b0 = bias[base + lr], b1 = bias[base + 16 + lr];
    const float b2 = bias[base + 32 + lr], b3 = bias[base + 48 + lr];
    const float QS = 0.125f * 1.4426950408889634f;  // 1/sqrt(dk) * log2(e), q only
#pragma unroll
    for (int m = 0; m < 4; ++m) {
      const int rowb = m0 + wm * 64 + m * 16 + lg * 4;
#pragma unroll
      for (int j = 0; j < 4; ++j) {
        const int t = (rowb + j) & 2047;
        const int bh = ((rowb + j) >> 11) * 8 + hh;
        float v0 = acc[m][0][j] + b0;
        float v1 = acc[m][1][j] + b1;
        float v2 = acc[m][2][j] + b2;
        float v3 = acc[m][3][j] + b3;
        if (which < 2) {
          const float2 cs0 = tab[t * 32 + lr];
          const float2 cs1 = tab[t * 32 + 16 + lr];
          float r0 = v0 * cs0.x - v2 * cs0.y;
          float r2 = v2 * cs0.x + v0 * cs0.y;
          float r1 = v1 * cs1.x - v3 * cs1.y;
          float r3 = v3 * cs1.x + v1 * cs1.y;
          if (which == 0) { r0 *= QS; r1 *= QS; r2 *= QS; r3 *= QS; }
          short* dst = (which == 0 ? qp : kp) + ((size_t)bh * TT + t) * 64;
          dst[lr] = f2b(r0); dst[16 + lr] = f2b(r1);
          dst[32 + lr] = f2b(r2); dst[48 + lr] = f2b(r3);
        } else {
          short* vb = vtp + (size_t)bh * 64 * TT + t;
          vb[(size_t)lr * TT] = f2b(v0);
          vb[(size_t)(16 + lr) * TT] = f2b(v1);
          vb[(size_t)(32 + lr) * TT] = f2b(v2);
          vb[(size_t)(48 + lr) * TT] = f2b(v3);
        }
      }
    }
  } else {
#pragma unroll
    for (int m = 0; m < 4; ++m)
#pragma unroll
      for (int n = 0; n < 4; ++n)
#pragma unroll
        for (int j = 0; j < 4; ++j) {
          const int row = m0 + wm * 64 + m * 16 + lg * 4 + j;
          const int col = n0 + wn * 64 + n * 16 + lr;
          ((float*)o0)[(size_t)row * 512 + col] = acc[m][n][j] + bias[col];
        }
  }
}

// Flash attention, swapped-QK^T 32x32x16, exp2 softmax, gll-staged pipeline.
// 8 waves x 32 q-rows = 256 q-rows/block. Depth-2: 2 K-tiles per barrier,
// 4-deep K/V LDS rings. [round-11 proven structure — unchanged]
__global__ __launch_bounds__(512) void attn_kernel(const short* __restrict__ q,
                                                   const short* __restrict__ k,
                                                   const short* __restrict__ vt,
                                                   const unsigned char* __restrict__ mask,
                                                   short* __restrict__ o) {
  __shared__ short Ks[4][64 * 64];
  __shared__ short Vs[4][64 * 64];
  __shared__ float psc[8][32];
  const int tid = threadIdx.x;
  const int lane = tid & 63, wave = tid >> 6;  // wave 0..7
  const int l31 = lane & 31, g = lane >> 5;
  const bool hi = (g != 0);
  // bijective XCD swizzle: 512 blocks, 8 XCDs -> 8 q-tiles of one bh per XCD
  const int nb = (blockIdx.x & 7) * 64 + (blockIdx.x >> 3);
  const int bh = nb >> 3, qt = nb & 7;
  const int bb = bh >> 3, hh = bh & 7;
  const int q0 = qt * 256 + wave * 32;
  const size_t bhT = (size_t)bh * TT;
  const unsigned char* maskb = mask + (size_t)bb * TT;

  // whole-row mask flag (hoisted)
  unsigned mor = 0;
  const unsigned* mw = (const unsigned*)maskb;
#pragma unroll
  for (int i = 0; i < 8; ++i) mor |= mw[lane + 64 * i];
  const bool masked = __any((int)(mor != 0));

  // Q as B-operand frags
  bf16x8 qf[4];
#pragma unroll
  for (int ds = 0; ds < 4; ++ds)
    qf[ds] = *reinterpret_cast<const bf16x8*>(q + (bhT + q0 + l31) * 64 + ds * 16 + g * 8);

  f32x16 oa0 = {}, oa1 = {};
  float m_run = 0.0f, l_run = 0.0f;

  // gll staging: wave w stages K rows [w*8, +8) and V d-rows [w*8, +8)
  const int swz_col = ((lane & 7) ^ ((lane >> 3) & 7)) * 8;
  const int r0 = wave * 8;
  const short* kg0 = k + (bhT + r0 + (lane >> 3)) * 64 + swz_col;
  const short* vg0 = vt + ((size_t)bh * 64 + r0 + (lane >> 3)) * TT + swz_col;

  auto stage = [&](int kt, int buf) {
    gll16(kg0 + (size_t)kt * 4096, &Ks[buf][r0 * 64]);
    gll16(vg0 + (size_t)kt * 64,   &Vs[buf][r0 * 64]);
  };

  auto tile = [&](int kt, const short* Kc, const short* Vc) {
    // S^T = K Q^T
    f32x16 s0 = {}, s1 = {};
    __builtin_amdgcn_s_setprio(1);
#pragma unroll
    for (int ds = 0; ds < 4; ++ds) {
      const int cb = ds * 32 + g * 16;
      const bf16x8 ka0 = lds16(Kc, l31, cb);
      const bf16x8 ka1 = lds16(Kc, 32 + l31, cb);
      s0 = __builtin_amdgcn_mfma_f32_32x32x16_bf16(ka0, qf[ds], s0, 0, 0, 0);
      s1 = __builtin_amdgcn_mfma_f32_32x32x16_bf16(ka1, qf[ds], s1, 0, 0, 0);
    }
    __builtin_amdgcn_s_setprio(0);

    if (masked) {
#pragma unroll
      for (int r = 0; r < 16; ++r) {
        const int kk = (r & 3) + 8 * (r >> 2) + 4 * g;
        if (maskb[kt * 64 + kk]) s0[r] += -1e30f;
        if (maskb[kt * 64 + 32 + kk]) s1[r] += -1e30f;
      }
    }

    // row max over 64 keys: max3 tree + cross-half
    float b8[8];
#pragma unroll
    for (int i = 0; i < 8; ++i) b8[i] = max3f(s0[i], s0[i + 8], s1[i]);
    float c4[4];
#pragma unroll
    for (int i = 0; i < 4; ++i) c4[i] = fmaxf(s1[8 + i], s1[12 + i]);
    const float d0 = max3f(b8[0], b8[1], b8[2]);
    const float d1 = max3f(b8[3], b8[4], b8[5]);
    const float d2 = max3f(b8[6], b8[7], c4[0]);
    const float d3 = max3f(c4[1], c4[2], c4[3]);
    const float mx = fmaxf(max3f(d0, d1, d2), d3);
    const float pmax = fmaxf(mx, __shfl_xor(mx, 32));

    if (kt == 0) {
      m_run = pmax;
    } else if (!__all((int)(pmax - m_run <= 8.0f))) {
      const float nm = fmaxf(m_run, pmax);
      const float sc = ex2(m_run - nm);
      m_run = nm;
      l_run *= sc;
      if (lane < 32) psc[wave][l31] = sc;
      asm volatile("s_waitcnt lgkmcnt(0)" ::: "memory");
#pragma unroll
      for (int r = 0; r < 16; ++r) {
        const float s = psc[wave][(r & 3) + 8 * (r >> 2) + 4 * g];
        oa0[r] *= s; oa1[r] *= s;
      }
    }

    // P = exp2(S - m) in place
#pragma unroll
    for (int i = 0; i < 16; ++i) { s0[i] = ex2(s0[i] - m_run); s1[i] = ex2(s1[i] - m_run); }

    // row sum (pairwise tree)
    float a8[8];
#pragma unroll
    for (int i = 0; i < 8; ++i) a8[i] = (s0[i] + s0[i + 8]) + (s1[i] + s1[i + 8]);
    const float e0 = (a8[0] + a8[1]) + (a8[2] + a8[3]);
    const float e1 = (a8[4] + a8[5]) + (a8[6] + a8[7]);
    const float rsum = e0 + e1;
    l_run += rsum + __shfl_xor(rsum, 32);

    // P -> bf16 A-frags in-register
    bf16x8 pa[4];
    p_to_frags(s0, hi, &pa[0], &pa[1]);
    p_to_frags(s1, hi, &pa[2], &pa[3]);

    // O += P V
    __builtin_amdgcn_s_setprio(1);
#pragma unroll
    for (int ks = 0; ks < 4; ++ks) {
      const int cb = ks * 32 + g * 16;
      const bf16x8 vb0 = lds16(Vc, l31, cb);
      const bf16x8 vb1 = lds16(Vc, 32 + l31, cb);
      oa0 = __builtin_amdgcn_mfma_f32_32x32x16_bf16(pa[ks], vb0, oa0, 0, 0, 0);
      oa1 = __builtin_amdgcn_mfma_f32_32x32x16_bf16(pa[ks], vb1, oa1, 0, 0, 0);
    }
    __builtin_amdgcn_s_setprio(0);
  };

  // prologue: stage tiles 0 and 1
  stage(0, 0);
  stage(1, 1);
  __syncthreads();

  for (int kt = 0; kt < TT / 64; kt += 2) {
    if (kt + 2 < TT / 64) stage(kt + 2, (kt + 2) & 3);
    if (kt + 3 < TT / 64) stage(kt + 3, (kt + 3) & 3);
    tile(kt,     Ks[kt & 3],       Vs[kt & 3]);
    tile(kt + 1, Ks[(kt + 1) & 3], Vs[(kt + 1) & 3]);
    __syncthreads();  // drains prefetch vmcnt; frees read slots for next ring pass
  }

  // epilogue: O[q][d] / l
  const float linv = 1.0f / l_run;  // valid for q = l31
#pragma unroll
  for (int r = 0; r < 16; ++r) {
    const int qr = (r & 3) + 8 * (r >> 2) + 4 * g;
    const float lv = __shfl(linv, (lane & 32) | qr, 64);
    const int trow = q0 + qr;
    const size_t orow = ((size_t)bb * TT + trow) * 512 + hh * 64 + l31;
    o[orow]      = f2b(oa0[r] * lv);
    o[orow + 32] = f2b(oa1[r] * lv);
  }
}

extern "C" void kernel_launch(void* const* d_in, const int* in_sizes, int n_in,
                              void* d_out, int out_size, void* d_ws, size_t ws_size,
                              hipStream_t stream) {
  (void)in_sizes; (void)n_in; (void)out_size; (void)ws_size;
  const float* x = (const float*)d_in[0];
  const unsigned char* mask = (const unsigned char*)d_in[1];
  const float* ln_w = (const float*)d_in[2];
  const float* ln_b = (const float*)d_in[3];
  const float* w_qkv = (const float*)d_in[4];
  const float* b_qkv = (const float*)d_in[5];
  const float* w_o = (const float*)d_in[6];
  const float* b_o = (const float*)d_in[7];
  float* out = (float*)d_out;

  char* ws = (char*)d_ws;
  short* h_buf = (short*)(ws);                 // 16384*512 bf16 = 16 MB; reused as attn_out
  short* wqkvT = (short*)(ws + 16777216);      // 1536*512 bf16
  short* woT   = (short*)(ws + 18350080);      // 512*512 bf16
  short* q_ws  = (short*)(ws + 18874368);      // [64][2048][64] bf16
  short* k_ws  = (short*)(ws + 35651584);      // [64][2048][64] bf16
  short* vt_ws = (short*)(ws + 52428800);      // [64][64][2048] bf16
  float2* tab  = (float2*)(ws + 69206016);     // [2048][32] float2 = 512 KB

  hipLaunchKernelGGL(prepln_kernel, dim3(8704), dim3(256), 0, stream,
                     x, ln_w, ln_b, h_buf, w_qkv, wqkvT, w_o, woT, tab);
  hipLaunchKernelGGL((gemm128_kernel<0>), dim3(128, 12), dim3(256), 0, stream,
                     h_buf, wqkvT, b_qkv, tab, (void*)q_ws, (void*)k_ws, (void*)vt_ws);
  hipLaunchKernelGGL(attn_kernel, dim3(512), dim3(512), 0, stream,
                     q_ws, k_ws, vt_ws, mask, h_buf);
  hipLaunchKernelGGL((gemm128_kernel<1>), dim3(128, 4), dim3(256), 0, stream,
                     h_buf, woT, b_o, tab, (void*)out, nullptr, nullptr);
}